// Round 1
// baseline (2757.328 us; speedup 1.0000x reference)
//
#include <hip/hip_runtime.h>
#include <math.h>

#define B_ 4
#define T_ 4096
#define D_ 1024
#define K_ 8
#define M_ 16          // candidates kept per row (top-M, refined to top-K)
#define BI 32          // i-tile rows
#define BJ 256         // j-tile cols
#define DC 32          // D chunk staged in LDS

// ---------------- Kernel 1: row norms (fp64 truth) ----------------
__global__ __launch_bounds__(256) void norm_kernel(const float* __restrict__ x,
                                                   float* __restrict__ rn32,
                                                   double* __restrict__ rn64) {
    const int row = blockIdx.x;                 // 0 .. B*T-1
    const int tid = threadIdx.x;                // 256 threads, 4 floats each
    const float4 v = reinterpret_cast<const float4*>(x + (size_t)row * D_)[tid];
    double ss = (double)v.x * v.x + (double)v.y * v.y +
                (double)v.z * v.z + (double)v.w * v.w;
    for (int o = 32; o > 0; o >>= 1) ss += __shfl_down(ss, o);
    __shared__ double ws[4];
    if ((tid & 63) == 0) ws[tid >> 6] = ss;
    __syncthreads();
    if (tid == 0) {
        double s = ws[0] + ws[1] + ws[2] + ws[3];
        double rn = 1.0 / (sqrt(s) + 1e-8);
        rn64[row] = rn;
        rn32[row] = (float)rn;
    }
}

// ---------------- Kernel 2: causal cosine sim + per-row top-16 ----------------
// Grid: B * 64 blocks (i-tile pairing t <-> 127-t balances the triangle: 17 j-tiles each).
__global__ __launch_bounds__(256) void simtopk_kernel(const float* __restrict__ x,
                                                      const float* __restrict__ rn32,
                                                      int* __restrict__ cand_idx,
                                                      float* __restrict__ cand_val) {
    // LDS: At[DC][36] + Bt[DC][260] staged; Cs[BI][260] aliased on top (barriered).
    __shared__ __align__(16) float smem[DC * 36 + DC * 260]; // 9472 floats = 37.9 KB
    float (*At)[36]  = reinterpret_cast<float(*)[36]>(smem);
    float (*Bt)[260] = reinterpret_cast<float(*)[260]>(smem + DC * 36);
    float (*Cs)[260] = reinterpret_cast<float(*)[260]>(smem);

    const int b   = blockIdx.x >> 6;
    const int p   = blockIdx.x & 63;
    const int tid = threadIdx.x;
    const int tx  = tid & 31;   // j-group: 32 groups * 8 j = 256
    const int ty  = tid >> 5;   // i-group: 8 groups * 4 i = 32
    const float* xb = x + (size_t)b * T_ * D_;
    const float* rb = rn32 + b * T_;

    for (int half = 0; half < 2; ++half) {
        const int t  = half ? (127 - p) : p;    // i-tile id within batch
        const int i0 = t * BI;

        float tv[M_]; int tix[M_];              // ascending: tv[0] = current min
#pragma unroll
        for (int k = 0; k < M_; ++k) { tv[k] = -INFINITY; tix[k] = -1; }

        const int njt = (t >> 3) + 1;           // ceil((i0+BI)/BJ)
        for (int jt = 0; jt < njt; ++jt) {
            const int j0 = jt * BJ;
            float acc[4][8];
#pragma unroll
            for (int ii = 0; ii < 4; ++ii)
#pragma unroll
                for (int jj = 0; jj < 8; ++jj) acc[ii][jj] = 0.f;

            for (int dc = 0; dc < D_; dc += DC) {
                __syncthreads();   // protects prior Cs reads / prior chunk reads
                // stage A (32 rows x 32 d), normalized, transposed into At[d][i]
                {
                    const int i  = tid >> 3;
                    const int dq = (tid & 7) * 4;
                    const float rn = rb[i0 + i];
                    float4 v = *reinterpret_cast<const float4*>(
                        &xb[(size_t)(i0 + i) * D_ + dc + dq]);
                    At[dq + 0][i] = v.x * rn;
                    At[dq + 1][i] = v.y * rn;
                    At[dq + 2][i] = v.z * rn;
                    At[dq + 3][i] = v.w * rn;
                }
                // stage B (256 rows x 32 d), normalized, transposed into Bt[d][j]
#pragma unroll
                for (int l = 0; l < 8; ++l) {
                    const int li = tid + l * 256;
                    const int j  = li >> 3;
                    const int dq = (li & 7) * 4;
                    const float rn = rb[j0 + j];
                    float4 v = *reinterpret_cast<const float4*>(
                        &xb[(size_t)(j0 + j) * D_ + dc + dq]);
                    Bt[dq + 0][j] = v.x * rn;
                    Bt[dq + 1][j] = v.y * rn;
                    Bt[dq + 2][j] = v.z * rn;
                    Bt[dq + 3][j] = v.w * rn;
                }
                __syncthreads();
#pragma unroll 8
                for (int d = 0; d < DC; ++d) {
                    float4 a  = *reinterpret_cast<const float4*>(&At[d][ty * 4]);
                    float4 b0 = *reinterpret_cast<const float4*>(&Bt[d][tx * 8]);
                    float4 b1 = *reinterpret_cast<const float4*>(&Bt[d][tx * 8 + 4]);
                    float av[4] = {a.x, a.y, a.z, a.w};
                    float bv[8] = {b0.x, b0.y, b0.z, b0.w, b1.x, b1.y, b1.z, b1.w};
#pragma unroll
                    for (int ii = 0; ii < 4; ++ii)
#pragma unroll
                        for (int jj = 0; jj < 8; ++jj)
                            acc[ii][jj] = fmaf(av[ii], bv[jj], acc[ii][jj]);
                }
            }
            __syncthreads();
            // dump sim tile to LDS (aliases At/Bt — done with them this tile)
#pragma unroll
            for (int ii = 0; ii < 4; ++ii) {
                *reinterpret_cast<float4*>(&Cs[ty * 4 + ii][tx * 8]) =
                    make_float4(acc[ii][0], acc[ii][1], acc[ii][2], acc[ii][3]);
                *reinterpret_cast<float4*>(&Cs[ty * 4 + ii][tx * 8 + 4]) =
                    make_float4(acc[ii][4], acc[ii][5], acc[ii][6], acc[ii][7]);
            }
            __syncthreads();
            // per-row top-M update (threads 0..31 own one row each)
            if (tid < BI) {
                const int gi   = i0 + tid;
                const int jmax = gi - j0;              // causal: j <= gi  (>=0 always)
                const int cend = jmax < BJ - 1 ? jmax : BJ - 1;
                for (int c = 0; c <= cend; ++c) {
                    const float v = Cs[tid][c];
                    if (v > tv[0]) {
                        const int nj = j0 + c;
                        // branch-free sorted insert, all indices compile-time
#pragma unroll
                        for (int k = 0; k < M_; ++k) {
                            const float nxt = (k < M_ - 1) ? tv[k + 1] : INFINITY;
                            const int   nxi = (k < M_ - 1) ? tix[k + 1] : -1;
                            const bool  up  = v > nxt;      // strict: ties keep lower index
                            const bool  mid = v > tv[k];
                            tv[k]  = up ? nxt : (mid ? v  : tv[k]);
                            tix[k] = up ? nxi : (mid ? nj : tix[k]);
                        }
                    }
                }
            }
        }
        // write candidates, descending value order
        if (tid < BI) {
            const int gi = i0 + tid;
            const size_t base = ((size_t)(b * T_ + gi)) * M_;
#pragma unroll
            for (int k = 0; k < M_; ++k) {
                cand_idx[base + k] = tix[M_ - 1 - k];
                cand_val[base + k] = tv[M_ - 1 - k];
            }
        }
    }
}

// ---------------- Kernel 3: margin-gated fp64 refine + gather + gate epilogue ----------------
__global__ __launch_bounds__(256) void epi_kernel(const float* __restrict__ x,
                                                  const double* __restrict__ rn64,
                                                  const int* __restrict__ cand_idx,
                                                  const float* __restrict__ cand_val,
                                                  const float* __restrict__ gain,
                                                  const float* __restrict__ bias,
                                                  const float* __restrict__ lmix,
                                                  const float* __restrict__ lscale,
                                                  float* __restrict__ out) {
    const int row = blockIdx.x;           // b*T + i
    const int b   = row >> 12;            // /T_
    const int tid = threadIdx.x;

    __shared__ int    s_idx[M_];
    __shared__ float  s_val[M_];
    __shared__ int    s_sel[K_];
    __shared__ int    s_cnt;
    __shared__ double s_red[M_ * 4];
    __shared__ double s_sim[M_];

    if (tid < M_) {
        s_idx[tid] = cand_idx[(size_t)row * M_ + tid];
        s_val[tid] = cand_val[(size_t)row * M_ + tid];
    }
    __syncthreads();

    int nvalid = 0;
#pragma unroll
    for (int k = 0; k < M_; ++k) nvalid += (s_idx[k] >= 0);
    const bool refine = (nvalid > K_) && (s_val[K_ - 1] - s_val[K_] < 1e-4f);

    const float4 xiv = reinterpret_cast<const float4*>(x + (size_t)row * D_)[tid];

    if (refine) {
        // exact fp64 sims for the 16 candidates
        double pd[M_];
#pragma unroll
        for (int c = 0; c < M_; ++c) {
            pd[c] = 0.0;
            const int j = s_idx[c];
            if (j >= 0) {
                const float4 xc = reinterpret_cast<const float4*>(
                    x + ((size_t)b * T_ + j) * D_)[tid];
                pd[c] = (double)xiv.x * xc.x + (double)xiv.y * xc.y +
                        (double)xiv.z * xc.z + (double)xiv.w * xc.w;
            }
        }
#pragma unroll
        for (int c = 0; c < M_; ++c) {
            double s = pd[c];
            for (int o = 32; o > 0; o >>= 1) s += __shfl_down(s, o);
            if ((tid & 63) == 0) s_red[c * 4 + (tid >> 6)] = s;
        }
        __syncthreads();
        if (tid < M_) {
            const double s = s_red[tid * 4] + s_red[tid * 4 + 1] +
                             s_red[tid * 4 + 2] + s_red[tid * 4 + 3];
            const int j = s_idx[tid];
            s_sim[tid] = (j >= 0) ? s * rn64[row] * rn64[b * T_ + j] : -INFINITY;
        }
        __syncthreads();
        if (tid == 0) {
            bool taken[M_];
            for (int c = 0; c < M_; ++c) taken[c] = false;
            int cnt = 0;
            for (int k = 0; k < K_; ++k) {
                int best = -1, bidx = 0x7fffffff;
                double bv = -1e300;
                for (int c = 0; c < M_; ++c) {
                    if (taken[c] || s_idx[c] < 0) continue;
                    const double v = s_sim[c];
                    if (v > bv || (v == bv && s_idx[c] < bidx)) {
                        bv = v; best = c; bidx = s_idx[c];
                    }
                }
                if (best >= 0) { taken[best] = true; s_sel[k] = s_idx[best]; ++cnt; }
                else s_sel[k] = -1;
            }
            s_cnt = cnt > 0 ? cnt : 1;
        }
    } else {
        if (tid == 0) {
            int cnt = 0;
            for (int k = 0; k < K_; ++k) { const int j = s_idx[k]; s_sel[k] = j; cnt += (j >= 0); }
            s_cnt = cnt > 0 ? cnt : 1;
        }
    }
    __syncthreads();

    // gather selected neighbors + mean
    float mx = 0.f, my = 0.f, mz = 0.f, mw = 0.f;
#pragma unroll
    for (int k = 0; k < K_; ++k) {
        const int j = s_sel[k];
        if (j >= 0) {
            const float4 xc = reinterpret_cast<const float4*>(
                x + ((size_t)b * T_ + j) * D_)[tid];
            mx += xc.x; my += xc.y; mz += xc.z; mw += xc.w;
        }
    }
    const float inv = 1.0f / (float)s_cnt;
    const float lm = lmix[0], ls = lscale[0];
    const float mix = 1.0f / (1.0f + expf(-lm));
    const float sc  = (fmaxf(ls, 0.f) + log1pf(expf(-fabsf(ls)))) + 0.01f;
    const float4 g  = reinterpret_cast<const float4*>(gain)[tid];
    const float4 bb = reinterpret_cast<const float4*>(bias)[tid];

    float4 o4;
    {
        float m, bl, y;
        m = mx * inv; bl = mix * xiv.x + (1.f - mix) * m; y = bl * g.x + bb.x;
        o4.x = 0.5f * y * (1.f + erff(y * 0.70710678118654752f)) * sc;
        m = my * inv; bl = mix * xiv.y + (1.f - mix) * m; y = bl * g.y + bb.y;
        o4.y = 0.5f * y * (1.f + erff(y * 0.70710678118654752f)) * sc;
        m = mz * inv; bl = mix * xiv.z + (1.f - mix) * m; y = bl * g.z + bb.z;
        o4.z = 0.5f * y * (1.f + erff(y * 0.70710678118654752f)) * sc;
        m = mw * inv; bl = mix * xiv.w + (1.f - mix) * m; y = bl * g.w + bb.w;
        o4.w = 0.5f * y * (1.f + erff(y * 0.70710678118654752f)) * sc;
    }
    reinterpret_cast<float4*>(out + (size_t)row * D_)[tid] = o4;
}

// ---------------- launch ----------------
extern "C" void kernel_launch(void* const* d_in, const int* in_sizes, int n_in,
                              void* d_out, int out_size, void* d_ws, size_t ws_size,
                              hipStream_t stream) {
    const float* x      = (const float*)d_in[0];
    const float* gain   = (const float*)d_in[1];
    const float* bias   = (const float*)d_in[2];
    const float* lmix   = (const float*)d_in[3];
    const float* lscale = (const float*)d_in[4];
    float* out = (float*)d_out;

    // workspace layout
    char* ws = (char*)d_ws;
    float*  rn32 = (float*)ws;                               // B*T floats   (64 KB)
    double* rn64 = (double*)(ws + 65536);                    // B*T doubles  (128 KB)
    int*    cidx = (int*)(ws + 65536 + 131072);              // B*T*16 ints  (1 MB)
    float*  cval = (float*)(ws + 65536 + 131072 + 1048576);  // B*T*16 floats(1 MB)

    norm_kernel<<<dim3(B_ * T_), dim3(256), 0, stream>>>(x, rn32, rn64);
    simtopk_kernel<<<dim3(B_ * 64), dim3(256), 0, stream>>>(x, rn32, cidx, cval);
    epi_kernel<<<dim3(B_ * T_), dim3(256), 0, stream>>>(x, rn64, cidx, cval,
                                                        gain, bias, lmix, lscale, out);
}

// Round 2
// 2578.227 us; speedup vs baseline: 1.0695x; 1.0695x over previous
//
#include <hip/hip_runtime.h>
#include <math.h>

#define B_ 4
#define T_ 4096
#define D_ 1024
#define K_ 8
#define M_ 12          // candidates kept per row/segment (top-M, refined to top-K)
#define BI 32          // i-tile rows
#define BJ 128         // j-tile cols
#define DC 32          // D chunk staged in LDS

// ---------------- Kernel 1: row norms (fp64 truth) ----------------
__global__ __launch_bounds__(256) void norm_kernel(const float* __restrict__ x,
                                                   float* __restrict__ rn32,
                                                   double* __restrict__ rn64) {
    const int row = blockIdx.x;                 // 0 .. B*T-1
    const int tid = threadIdx.x;                // 256 threads, 4 floats each
    const float4 v = reinterpret_cast<const float4*>(x + (size_t)row * D_)[tid];
    double ss = (double)v.x * v.x + (double)v.y * v.y +
                (double)v.z * v.z + (double)v.w * v.w;
    for (int o = 32; o > 0; o >>= 1) ss += __shfl_down(ss, o);
    __shared__ double ws[4];
    if ((tid & 63) == 0) ws[tid >> 6] = ss;
    __syncthreads();
    if (tid == 0) {
        double s = ws[0] + ws[1] + ws[2] + ws[3];
        double rn = 1.0 / (sqrt(s) + 1e-8);
        rn64[row] = rn;
        rn32[row] = (float)rn;
    }
}

// ---------------- Kernel 2: causal cosine sim + per-segment top-M ----------------
// Block = (b, i-tile t of 32 rows, j-segment s covering SEGJT j-tiles of 128).
// Grid: B * 128 * NSEGMAX; blocks with s*SEGJT >= njt(t) exit immediately.
__global__ __launch_bounds__(256) void simtopk_kernel(const float* __restrict__ x,
                                                      const float* __restrict__ rn32,
                                                      int* __restrict__ cand_idx,
                                                      float* __restrict__ cand_val,
                                                      int SEGJT, int NSEGMAX) {
    // LDS: At[DC][36] + Bt[DC][132] staged (5376 floats = 21.5 KB);
    // Cs[BI][132] (4224 floats) aliased over the base (barriered).
    __shared__ __align__(16) float smem[DC * 36 + DC * 132];
    float (*At)[36]  = reinterpret_cast<float(*)[36]>(smem);
    float (*Bt)[132] = reinterpret_cast<float(*)[132]>(smem + DC * 36);
    float (*Cs)[132] = reinterpret_cast<float(*)[132]>(smem);

    const int bid = blockIdx.x;
    const int s   = bid % NSEGMAX;
    const int bt  = bid / NSEGMAX;
    const int t   = bt & 127;
    const int b   = bt >> 7;
    const int njt = (t >> 2) + 1;               // j-tiles needed: floor((32t+31)/128)+1
    const int jt0 = s * SEGJT;
    if (jt0 >= njt) return;
    const int jt1 = min(jt0 + SEGJT, njt);
    const int i0  = t * BI;

    const int tid = threadIdx.x;
    const int tx  = tid & 31;   // owns j columns 4*tx .. 4*tx+3 (consecutive -> conflict-free b128)
    const int ty  = tid >> 5;   // owns i rows    4*ty .. 4*ty+3
    const float* xb = x + (size_t)b * T_ * D_;
    const float* rb = rn32 + b * T_;

    const int ai  = tid >> 3;          // A-stage row 0..31
    const int adq = (tid & 7) << 2;    // A-stage d offset

    float tv[M_]; int tix[M_];         // ascending: tv[0] = current min
#pragma unroll
    for (int k = 0; k < M_; ++k) { tv[k] = -INFINITY; tix[k] = -1; }

    for (int jt = jt0; jt < jt1; ++jt) {
        const int j0 = jt << 7;
        float acc[4][4];
#pragma unroll
        for (int ii = 0; ii < 4; ++ii)
#pragma unroll
            for (int jj = 0; jj < 4; ++jj) acc[ii][jj] = 0.f;

        for (int dc = 0; dc < D_; dc += DC) {
            __syncthreads();   // protects prior Cs reads / prior chunk reads
            // stage A (32 rows x 32 d), normalized, transposed into At[d][i]
            {
                const float rn = rb[i0 + ai];
                float4 v = *reinterpret_cast<const float4*>(
                    &xb[(size_t)(i0 + ai) * D_ + dc + adq]);
                At[adq + 0][ai] = v.x * rn;
                At[adq + 1][ai] = v.y * rn;
                At[adq + 2][ai] = v.z * rn;
                At[adq + 3][ai] = v.w * rn;
            }
            // stage B (128 rows x 32 d), normalized, transposed into Bt[d][j]
#pragma unroll
            for (int l = 0; l < 4; ++l) {
                const int li = tid + (l << 8);
                const int j  = li >> 3;
                const int dq = (li & 7) << 2;
                const float rn = rb[j0 + j];
                float4 v = *reinterpret_cast<const float4*>(
                    &xb[(size_t)(j0 + j) * D_ + dc + dq]);
                Bt[dq + 0][j] = v.x * rn;
                Bt[dq + 1][j] = v.y * rn;
                Bt[dq + 2][j] = v.z * rn;
                Bt[dq + 3][j] = v.w * rn;
            }
            __syncthreads();
#pragma unroll 8
            for (int d = 0; d < DC; ++d) {
                float4 a  = *reinterpret_cast<const float4*>(&At[d][ty << 2]);
                float4 bv = *reinterpret_cast<const float4*>(&Bt[d][tx << 2]);
                float av[4] = {a.x, a.y, a.z, a.w};
                float bw[4] = {bv.x, bv.y, bv.z, bv.w};
#pragma unroll
                for (int ii = 0; ii < 4; ++ii)
#pragma unroll
                    for (int jj = 0; jj < 4; ++jj)
                        acc[ii][jj] = fmaf(av[ii], bw[jj], acc[ii][jj]);
            }
        }
        __syncthreads();
        // dump sim tile to LDS (aliases At/Bt — done with them this tile)
#pragma unroll
        for (int ii = 0; ii < 4; ++ii) {
            *reinterpret_cast<float4*>(&Cs[(ty << 2) + ii][tx << 2]) =
                make_float4(acc[ii][0], acc[ii][1], acc[ii][2], acc[ii][3]);
        }
        __syncthreads();
        // per-row top-M update (threads 0..31 own one row each)
        if (tid < BI) {
            const int gi   = i0 + tid;
            const int jmax = gi - j0;              // causal: j <= gi (>= 0 since jt < njt)
            const int cend = jmax < BJ - 1 ? jmax : BJ - 1;
            for (int c = 0; c <= cend; ++c) {
                const float v = Cs[tid][c];
                if (v > tv[0]) {
                    const int nj = j0 + c;
#pragma unroll
                    for (int k = 0; k < M_; ++k) {
                        const float nxt = (k < M_ - 1) ? tv[k + 1] : INFINITY;
                        const int   nxi = (k < M_ - 1) ? tix[k + 1] : -1;
                        const bool  up  = v > nxt;      // strict: ties keep lower index
                        const bool  mid = v > tv[k];
                        tv[k]  = up ? nxt : (mid ? v  : tv[k]);
                        tix[k] = up ? nxi : (mid ? nj : tix[k]);
                    }
                }
            }
        }
    }
    // write per-segment candidates, descending value order
    if (tid < BI) {
        const size_t base = ((size_t)(b * T_ + i0 + tid) * NSEGMAX + s) * M_;
#pragma unroll
        for (int k = 0; k < M_; ++k) {
            cand_idx[base + k] = tix[M_ - 1 - k];
            cand_val[base + k] = tv[M_ - 1 - k];
        }
    }
}

// ---------------- Kernel 3: segment merge + fp64 refine + gather + gate epilogue ----------------
__global__ __launch_bounds__(256) void epi_kernel(const float* __restrict__ x,
                                                  const double* __restrict__ rn64,
                                                  const int* __restrict__ cand_idx,
                                                  const float* __restrict__ cand_val,
                                                  const float* __restrict__ gain,
                                                  const float* __restrict__ bias,
                                                  const float* __restrict__ lmix,
                                                  const float* __restrict__ lscale,
                                                  float* __restrict__ out,
                                                  int SEGJT, int NSEGMAX) {
    const int row = blockIdx.x;           // b*T + i
    const int b   = row >> 12;            // /T_
    const int i   = row & (T_ - 1);
    const int tid = threadIdx.x;
    const int t   = i >> 5;
    const int njt = (t >> 2) + 1;
    const int nseg = (njt + SEGJT - 1) / SEGJT;   // segments actually written

    __shared__ float  m_val[9 * M_];
    __shared__ int    m_idx[9 * M_];
    __shared__ int    s_idx[M_];
    __shared__ float  s_val[M_];
    __shared__ int    s_sel[K_];
    __shared__ int    s_cnt;
    __shared__ double s_red[M_ * 4];
    __shared__ double s_sim[M_];

    const int ncand = nseg * M_;          // <= 108
    if (tid < ncand) {
        const size_t base = ((size_t)row * NSEGMAX + (tid / M_)) * M_ + (tid % M_);
        m_idx[tid] = cand_idx[base];
        m_val[tid] = cand_val[base];
    }
    __syncthreads();
    if (tid == 0) {
        // merge segment lists (ascending-j segment order, desc within -> tie rule preserved)
        float gv[M_]; int gx[M_];
#pragma unroll
        for (int k = 0; k < M_; ++k) { gv[k] = -INFINITY; gx[k] = -1; }
        for (int c = 0; c < ncand; ++c) {
            const float v = m_val[c]; const int nj = m_idx[c];
            if (nj >= 0 && v > gv[0]) {
#pragma unroll
                for (int k = 0; k < M_; ++k) {
                    const float nxt = (k < M_ - 1) ? gv[k + 1] : INFINITY;
                    const int   nxi = (k < M_ - 1) ? gx[k + 1] : -1;
                    const bool  up  = v > nxt;
                    const bool  mid = v > gv[k];
                    gv[k] = up ? nxt : (mid ? v  : gv[k]);
                    gx[k] = up ? nxi : (mid ? nj : gx[k]);
                }
            }
        }
#pragma unroll
        for (int k = 0; k < M_; ++k) { s_val[k] = gv[M_ - 1 - k]; s_idx[k] = gx[M_ - 1 - k]; }
    }
    __syncthreads();

    int nvalid = 0;
#pragma unroll
    for (int k = 0; k < M_; ++k) nvalid += (s_idx[k] >= 0);
    const bool refine = (nvalid > K_) && (s_val[K_ - 1] - s_val[K_] < 2e-4f);

    const float4 xiv = reinterpret_cast<const float4*>(x + (size_t)row * D_)[tid];

    if (refine) {
        // exact fp64 sims for the M candidates
        double pd[M_];
#pragma unroll
        for (int c = 0; c < M_; ++c) {
            pd[c] = 0.0;
            const int j = s_idx[c];
            if (j >= 0) {
                const float4 xc = reinterpret_cast<const float4*>(
                    x + ((size_t)b * T_ + j) * D_)[tid];
                pd[c] = (double)xiv.x * xc.x + (double)xiv.y * xc.y +
                        (double)xiv.z * xc.z + (double)xiv.w * xc.w;
            }
        }
#pragma unroll
        for (int c = 0; c < M_; ++c) {
            double s = pd[c];
            for (int o = 32; o > 0; o >>= 1) s += __shfl_down(s, o);
            if ((tid & 63) == 0) s_red[c * 4 + (tid >> 6)] = s;
        }
        __syncthreads();
        if (tid < M_) {
            const double s = s_red[tid * 4] + s_red[tid * 4 + 1] +
                             s_red[tid * 4 + 2] + s_red[tid * 4 + 3];
            const int j = s_idx[tid];
            s_sim[tid] = (j >= 0) ? s * rn64[row] * rn64[b * T_ + j] : -INFINITY;
        }
        __syncthreads();
        if (tid == 0) {
            bool taken[M_];
#pragma unroll
            for (int c = 0; c < M_; ++c) taken[c] = false;
            int cnt = 0;
            for (int k = 0; k < K_; ++k) {
                int best = -1, bidx = 0x7fffffff;
                double bv = -1e300;
                for (int c = 0; c < M_; ++c) {
                    if (taken[c] || s_idx[c] < 0) continue;
                    const double v = s_sim[c];
                    if (v > bv || (v == bv && s_idx[c] < bidx)) {
                        bv = v; best = c; bidx = s_idx[c];
                    }
                }
                if (best >= 0) { taken[best] = true; s_sel[k] = s_idx[best]; ++cnt; }
                else s_sel[k] = -1;
            }
            s_cnt = cnt > 0 ? cnt : 1;
        }
    } else {
        if (tid == 0) {
            int cnt = 0;
            for (int k = 0; k < K_; ++k) { const int j = s_idx[k]; s_sel[k] = j; cnt += (j >= 0); }
            s_cnt = cnt > 0 ? cnt : 1;
        }
    }
    __syncthreads();

    // gather selected neighbors + mean
    float mx = 0.f, my = 0.f, mz = 0.f, mw = 0.f;
#pragma unroll
    for (int k = 0; k < K_; ++k) {
        const int j = s_sel[k];
        if (j >= 0) {
            const float4 xc = reinterpret_cast<const float4*>(
                x + ((size_t)b * T_ + j) * D_)[tid];
            mx += xc.x; my += xc.y; mz += xc.z; mw += xc.w;
        }
    }
    const float inv = 1.0f / (float)s_cnt;
    const float lm = lmix[0], ls = lscale[0];
    const float mix = 1.0f / (1.0f + expf(-lm));
    const float sc  = (fmaxf(ls, 0.f) + log1pf(expf(-fabsf(ls)))) + 0.01f;
    const float4 g  = reinterpret_cast<const float4*>(gain)[tid];
    const float4 bb = reinterpret_cast<const float4*>(bias)[tid];

    float4 o4;
    {
        float m, bl, y;
        m = mx * inv; bl = mix * xiv.x + (1.f - mix) * m; y = bl * g.x + bb.x;
        o4.x = 0.5f * y * (1.f + erff(y * 0.70710678118654752f)) * sc;
        m = my * inv; bl = mix * xiv.y + (1.f - mix) * m; y = bl * g.y + bb.y;
        o4.y = 0.5f * y * (1.f + erff(y * 0.70710678118654752f)) * sc;
        m = mz * inv; bl = mix * xiv.z + (1.f - mix) * m; y = bl * g.z + bb.z;
        o4.z = 0.5f * y * (1.f + erff(y * 0.70710678118654752f)) * sc;
        m = mw * inv; bl = mix * xiv.w + (1.f - mix) * m; y = bl * g.w + bb.w;
        o4.w = 0.5f * y * (1.f + erff(y * 0.70710678118654752f)) * sc;
    }
    reinterpret_cast<float4*>(out + (size_t)row * D_)[tid] = o4;
}

// ---------------- launch ----------------
extern "C" void kernel_launch(void* const* d_in, const int* in_sizes, int n_in,
                              void* d_out, int out_size, void* d_ws, size_t ws_size,
                              hipStream_t stream) {
    const float* x      = (const float*)d_in[0];
    const float* gain   = (const float*)d_in[1];
    const float* bias   = (const float*)d_in[2];
    const float* lmix   = (const float*)d_in[3];
    const float* lscale = (const float*)d_in[4];
    float* out = (float*)d_out;

    // segmented config if workspace allows (deterministic: ws_size fixed per run)
    const size_t cand_elems_full = (size_t)B_ * T_ * 9 * M_;      // NSEGMAX=9
    const size_t need_full = 196608 + cand_elems_full * 8;        // idx(4B)+val(4B)
    int SEGJT, NSEGMAX;
    if (ws_size >= need_full) { SEGJT = 4;  NSEGMAX = 9; }
    else                      { SEGJT = 33; NSEGMAX = 1; }        // fallback: 1 segment

    char* ws = (char*)d_ws;
    float*  rn32 = (float*)ws;                                    // B*T floats  (64 KB)
    double* rn64 = (double*)(ws + 65536);                         // B*T doubles (128 KB)
    int*    cidx = (int*)(ws + 196608);                           // B*T*NSEGMAX*M ints
    float*  cval = (float*)(ws + 196608 + (size_t)B_ * T_ * NSEGMAX * M_ * 4);

    norm_kernel<<<dim3(B_ * T_), dim3(256), 0, stream>>>(x, rn32, rn64);
    simtopk_kernel<<<dim3(B_ * 128 * NSEGMAX), dim3(256), 0, stream>>>(
        x, rn32, cidx, cval, SEGJT, NSEGMAX);
    epi_kernel<<<dim3(B_ * T_), dim3(256), 0, stream>>>(x, rn64, cidx, cval,
                                                        gain, bias, lmix, lscale, out,
                                                        SEGJT, NSEGMAX);
}

// Round 3
// 1489.668 us; speedup vs baseline: 1.8510x; 1.7307x over previous
//
#include <hip/hip_runtime.h>
#include <math.h>

#define B_ 4
#define T_ 4096
#define D_ 1024
#define K_ 8
#define M_ 12          // candidates kept per row (refined to top-K)

// fallback fp32-path tile params (round-2 kernel)
#define BI 32
#define BJ 128
#define DC 32

typedef __attribute__((ext_vector_type(8))) short bf16x8;
typedef __attribute__((ext_vector_type(16))) float f32x16;

// branch-free sorted insert into ascending top-12 (tv[0]=min). Static indices.
__device__ __forceinline__ void ins12(float (&tv)[M_], int (&tix)[M_], float v, int nj) {
#pragma unroll
    for (int k = 0; k < M_; ++k) {
        const float nxt = (k < M_ - 1) ? tv[k + 1] : INFINITY;
        const int   nxi = (k < M_ - 1) ? tix[k + 1] : -1;
        const bool  up  = v > nxt;
        const bool  mid = v > tv[k];
        tv[k]  = up ? nxt : (mid ? v  : tv[k]);
        tix[k] = up ? nxi : (mid ? nj : tix[k]);
    }
}

__device__ __forceinline__ unsigned short f2bf_rne(float f) {
    unsigned u = __float_as_uint(f);
    unsigned r = (u + 0x7FFFu + ((u >> 16) & 1u)) >> 16;
    return (unsigned short)r;
}

// ---------------- Kernel 1: row norms (fp64 truth) + optional bf16 hi/lo prep ----------------
__global__ __launch_bounds__(256) void norm_prep_kernel(const float* __restrict__ x,
                                                        float* __restrict__ rn32,
                                                        double* __restrict__ rn64,
                                                        unsigned short* __restrict__ xh,
                                                        unsigned short* __restrict__ xl,
                                                        int do_prep) {
    const int row = blockIdx.x;
    const int tid = threadIdx.x;
    const float4 v = reinterpret_cast<const float4*>(x + (size_t)row * D_)[tid];
    double ss = (double)v.x * v.x + (double)v.y * v.y +
                (double)v.z * v.z + (double)v.w * v.w;
    for (int o = 32; o > 0; o >>= 1) ss += __shfl_down(ss, o);
    __shared__ double ws[4];
    __shared__ double s_rn;
    if ((tid & 63) == 0) ws[tid >> 6] = ss;
    __syncthreads();
    if (tid == 0) {
        double s = ws[0] + ws[1] + ws[2] + ws[3];
        double rn = 1.0 / (sqrt(s) + 1e-8);
        rn64[row] = rn;
        rn32[row] = (float)rn;
        s_rn = rn;
    }
    __syncthreads();
    if (do_prep) {
        const float rnf = (float)s_rn;
        float vn[4] = {v.x * rnf, v.y * rnf, v.z * rnf, v.w * rnf};
        ushort4 h, l;
        unsigned short* hp = &h.x; unsigned short* lp = &l.x;
#pragma unroll
        for (int e = 0; e < 4; ++e) {
            unsigned short hb = f2bf_rne(vn[e]);
            float hf = __uint_as_float(((unsigned)hb) << 16);
            hp[e] = hb;
            lp[e] = f2bf_rne(vn[e] - hf);
        }
        reinterpret_cast<ushort4*>(xh + (size_t)row * D_)[tid] = h;
        reinterpret_cast<ushort4*>(xl + (size_t)row * D_)[tid] = l;
    }
}

// ---------------- Kernel 2a: MFMA hi/lo similarity + per-segment top-M ----------------
// Block: 256 thr (4 waves), S-tile 64(i) x 256(j), wave tile 64x64, 32x32x16 bf16 MFMA.
// Grid: B * 64 * NSEGMAX; seg s covers j-tiles [s*SEGJT, min(njt, s*SEGJT+SEGJT)).
__global__ __launch_bounds__(256, 2) void simtopk_mfma(const unsigned short* __restrict__ xh,
                                                       const unsigned short* __restrict__ xl,
                                                       int* __restrict__ cand_idx,
                                                       float* __restrict__ cand_val,
                                                       int SEGJT, int NSEGMAX) {
    extern __shared__ char sm[];
    const int bid = blockIdx.x;
    const int s   = bid % NSEGMAX;
    const int bt  = bid / NSEGMAX;
    const int t   = bt & 63;
    const int b   = bt >> 6;
    const int njt = (t >> 2) + 1;              // j-tiles of 256 needed for rows [64t, 64t+63]
    const int jt0 = s * SEGJT;
    if (jt0 >= njt) return;
    const int jt1 = min(jt0 + SEGJT, njt);
    const int i0  = t << 6;

    const int tid  = threadIdx.x;
    const int lane = tid & 63;
    const int wc   = tid >> 6;     // wave id = 64-col group
    const int l31  = lane & 31;
    const int lhi  = lane >> 5;

    const unsigned short* xhb = xh + (size_t)b * T_ * D_;
    const unsigned short* xlb = xl + (size_t)b * T_ * D_;

    // LDS byte regions (80 KB dynamic): staging panels; S-tile (64KB f32) aliases base.
    char* Ah = sm;               // 64 x 64 bf16 = 8KB
    char* Al = sm + 8192;        // 8KB
    char* Bh = sm + 16384;       // 256 x 64 bf16 = 32KB
    char* Bl = sm + 49152;       // 32KB
    float* Sf = (float*)sm;      // 64 x 256 f32 = 64KB (alias)

    // scan identity: 4 scanners per row
    const int srow = tid >> 2;   // 0..63
    const int stc  = tid & 3;    // col quarter
    const int gi   = i0 + srow;
    const int r7   = srow & 7;

    float tv[M_]; int tix[M_];
#pragma unroll
    for (int k = 0; k < M_; ++k) { tv[k] = -INFINITY; tix[k] = -1; }

    for (int jt = jt0; jt < jt1; ++jt) {
        const int j0 = jt << 8;
        f32x16 acc[2][2];
#pragma unroll
        for (int m = 0; m < 2; ++m)
#pragma unroll
            for (int n = 0; n < 2; ++n)
#pragma unroll
                for (int r = 0; r < 16; ++r) acc[m][n][r] = 0.f;

        for (int dc = 0; dc < D_; dc += 64) {
            __syncthreads();   // protects S/stage reuse from previous phase
            // stage A panel chunk: 64 rows x 64 k (groups of 8 bf16 = 16B)
#pragma unroll
            for (int it = 0; it < 2; ++it) {
                const int g   = tid + (it << 8);
                const int row = g >> 3, kg = g & 7;
                const size_t ga = (size_t)(i0 + row) * D_ + dc + (kg << 3);
                const uint4 vh = *reinterpret_cast<const uint4*>(xhb + ga);
                const uint4 vl = *reinterpret_cast<const uint4*>(xlb + ga);
                const int off = row * 128 + ((kg ^ (row & 7)) << 4);
                *reinterpret_cast<uint4*>(Ah + off) = vh;
                *reinterpret_cast<uint4*>(Al + off) = vl;
            }
            // stage B panel chunk: 256 rows x 64 k
#pragma unroll
            for (int it = 0; it < 8; ++it) {
                const int g   = tid + (it << 8);
                const int row = g >> 3, kg = g & 7;
                const size_t ga = (size_t)(j0 + row) * D_ + dc + (kg << 3);
                const uint4 vh = *reinterpret_cast<const uint4*>(xhb + ga);
                const uint4 vl = *reinterpret_cast<const uint4*>(xlb + ga);
                const int off = row * 128 + ((kg ^ (row & 7)) << 4);
                *reinterpret_cast<uint4*>(Bh + off) = vh;
                *reinterpret_cast<uint4*>(Bl + off) = vl;
            }
            __syncthreads();
#pragma unroll
            for (int ks = 0; ks < 4; ++ks) {
                const int kg = (ks << 1) + lhi;
                bf16x8 ah[2], al2[2], bh2[2], bl2[2];
#pragma unroll
                for (int m = 0; m < 2; ++m) {
                    const int row = (m << 5) + l31;
                    const int off = row * 128 + ((kg ^ (row & 7)) << 4);
                    ah[m]  = *reinterpret_cast<bf16x8*>(Ah + off);
                    al2[m] = *reinterpret_cast<bf16x8*>(Al + off);
                }
#pragma unroll
                for (int n = 0; n < 2; ++n) {
                    const int row = (wc << 6) + (n << 5) + l31;
                    const int off = row * 128 + ((kg ^ (row & 7)) << 4);
                    bh2[n] = *reinterpret_cast<bf16x8*>(Bh + off);
                    bl2[n] = *reinterpret_cast<bf16x8*>(Bl + off);
                }
#pragma unroll
                for (int m = 0; m < 2; ++m)
#pragma unroll
                    for (int n = 0; n < 2; ++n) {
                        acc[m][n] = __builtin_amdgcn_mfma_f32_32x32x16_bf16(ah[m],  bh2[n], acc[m][n], 0, 0, 0);
                        acc[m][n] = __builtin_amdgcn_mfma_f32_32x32x16_bf16(ah[m],  bl2[n], acc[m][n], 0, 0, 0);
                        acc[m][n] = __builtin_amdgcn_mfma_f32_32x32x16_bf16(al2[m], bh2[n], acc[m][n], 0, 0, 0);
                    }
            }
        }
        __syncthreads();   // staging dead; write S (swizzled fcol4 ^= row&7)
#pragma unroll
        for (int m = 0; m < 2; ++m)
#pragma unroll
            for (int n = 0; n < 2; ++n)
#pragma unroll
                for (int r = 0; r < 16; ++r) {
                    const int row = (m << 5) + (r & 3) + ((r >> 2) << 3) + (lhi << 2);
                    const int col = (wc << 6) + (n << 5) + l31;
                    const int word = (row << 8) + ((((col >> 2) ^ (row & 7)) << 2) | (col & 3));
                    Sf[word] = acc[m][n][r];
                }
        __syncthreads();
        // scan: each scanner covers 64 cols of its row
#pragma unroll 2
        for (int c4 = 0; c4 < 16; ++c4) {
            const int fc4  = (stc << 4) | c4;
            const int word = (srow << 8) + ((fc4 ^ r7) << 2);
            const float4 v4 = *reinterpret_cast<float4*>(Sf + word);
            const int jb = j0 + (stc << 6) + (c4 << 2);
            const float a0 = (jb + 0 <= gi) ? v4.x : -INFINITY;
            const float a1 = (jb + 1 <= gi) ? v4.y : -INFINITY;
            const float a2 = (jb + 2 <= gi) ? v4.z : -INFINITY;
            const float a3 = (jb + 3 <= gi) ? v4.w : -INFINITY;
            const float mx = fmaxf(fmaxf(a0, a1), fmaxf(a2, a3));
            if (mx > tv[0]) {
                if (a0 > tv[0]) ins12(tv, tix, a0, jb + 0);
                if (a1 > tv[0]) ins12(tv, tix, a1, jb + 1);
                if (a2 > tv[0]) ins12(tv, tix, a2, jb + 2);
                if (a3 > tv[0]) ins12(tv, tix, a3, jb + 3);
            }
        }
    }
    // merge 4 scanner lists per row -> global top-12; mv/mi alias LDS (S dead)
    __syncthreads();
    float* mv = (float*)sm;              // 64*4*12 f32 = 12KB
    int*   mi = (int*)(sm + 12288);      // 12KB
    {
        const int base = (srow * 4 + stc) * M_;
#pragma unroll
        for (int k = 0; k < M_; ++k) { mv[base + k] = tv[k]; mi[base + k] = tix[k]; }
    }
    __syncthreads();
    if (stc == 0) {
        float gv[M_]; int gx[M_];
#pragma unroll
        for (int k = 0; k < M_; ++k) { gv[k] = -INFINITY; gx[k] = -1; }
        for (int sc = 0; sc < 4; ++sc) {
            const int base = (srow * 4 + sc) * M_;
            for (int k = M_ - 1; k >= 0; --k) {   // descending within list
                const float v = mv[base + k];
                if (!(v > gv[0])) break;          // rest smaller
                const int nj = mi[base + k];
                if (nj >= 0) ins12(gv, gx, v, nj);
            }
        }
        const size_t cb = ((size_t)(b * T_ + gi) * NSEGMAX + s) * M_;
#pragma unroll
        for (int k = 0; k < M_; ++k) {
            cand_val[cb + k] = gv[M_ - 1 - k];
            cand_idx[cb + k] = gx[M_ - 1 - k];
        }
    }
}

// ---------------- Kernel 2b: fp32 fallback (round-2 kernel, used only if ws too small) ----------------
__global__ __launch_bounds__(256) void simtopk_fp32(const float* __restrict__ x,
                                                    const float* __restrict__ rn32,
                                                    int* __restrict__ cand_idx,
                                                    float* __restrict__ cand_val,
                                                    int SEGJT, int NSEGMAX) {
    __shared__ __align__(16) float smem[DC * 36 + DC * 132];
    float (*At)[36]  = reinterpret_cast<float(*)[36]>(smem);
    float (*Bt)[132] = reinterpret_cast<float(*)[132]>(smem + DC * 36);
    float (*Cs)[132] = reinterpret_cast<float(*)[132]>(smem);

    const int bid = blockIdx.x;
    const int s   = bid % NSEGMAX;
    const int bt  = bid / NSEGMAX;
    const int t   = bt & 127;
    const int b   = bt >> 7;
    const int njt = (t >> 2) + 1;
    const int jt0 = s * SEGJT;
    if (jt0 >= njt) return;
    const int jt1 = min(jt0 + SEGJT, njt);
    const int i0  = t * BI;

    const int tid = threadIdx.x;
    const int tx  = tid & 31;
    const int ty  = tid >> 5;
    const float* xb = x + (size_t)b * T_ * D_;
    const float* rb = rn32 + b * T_;

    const int ai  = tid >> 3;
    const int adq = (tid & 7) << 2;

    float tv[M_]; int tix[M_];
#pragma unroll
    for (int k = 0; k < M_; ++k) { tv[k] = -INFINITY; tix[k] = -1; }

    for (int jt = jt0; jt < jt1; ++jt) {
        const int j0 = jt << 7;
        float acc[4][4];
#pragma unroll
        for (int ii = 0; ii < 4; ++ii)
#pragma unroll
            for (int jj = 0; jj < 4; ++jj) acc[ii][jj] = 0.f;

        for (int dc = 0; dc < D_; dc += DC) {
            __syncthreads();
            {
                const float rn = rb[i0 + ai];
                float4 v = *reinterpret_cast<const float4*>(&xb[(size_t)(i0 + ai) * D_ + dc + adq]);
                At[adq + 0][ai] = v.x * rn;
                At[adq + 1][ai] = v.y * rn;
                At[adq + 2][ai] = v.z * rn;
                At[adq + 3][ai] = v.w * rn;
            }
#pragma unroll
            for (int l = 0; l < 4; ++l) {
                const int li = tid + (l << 8);
                const int j  = li >> 3;
                const int dq = (li & 7) << 2;
                const float rn = rb[j0 + j];
                float4 v = *reinterpret_cast<const float4*>(&xb[(size_t)(j0 + j) * D_ + dc + dq]);
                Bt[dq + 0][j] = v.x * rn;
                Bt[dq + 1][j] = v.y * rn;
                Bt[dq + 2][j] = v.z * rn;
                Bt[dq + 3][j] = v.w * rn;
            }
            __syncthreads();
#pragma unroll 8
            for (int d = 0; d < DC; ++d) {
                float4 a  = *reinterpret_cast<const float4*>(&At[d][ty << 2]);
                float4 bv = *reinterpret_cast<const float4*>(&Bt[d][tx << 2]);
                float av[4] = {a.x, a.y, a.z, a.w};
                float bw[4] = {bv.x, bv.y, bv.z, bv.w};
#pragma unroll
                for (int ii = 0; ii < 4; ++ii)
#pragma unroll
                    for (int jj = 0; jj < 4; ++jj)
                        acc[ii][jj] = fmaf(av[ii], bw[jj], acc[ii][jj]);
            }
        }
        __syncthreads();
#pragma unroll
        for (int ii = 0; ii < 4; ++ii) {
            *reinterpret_cast<float4*>(&Cs[(ty << 2) + ii][tx << 2]) =
                make_float4(acc[ii][0], acc[ii][1], acc[ii][2], acc[ii][3]);
        }
        __syncthreads();
        if (tid < BI) {
            const int gi   = i0 + tid;
            const int jmax = gi - j0;
            const int cend = jmax < BJ - 1 ? jmax : BJ - 1;
            for (int c = 0; c <= cend; ++c) {
                const float v = Cs[tid][c];
                if (v > tv[0]) ins12(tv, tix, v, j0 + c);
            }
        }
    }
    if (tid < BI) {
        const size_t base = ((size_t)(b * T_ + i0 + tid) * NSEGMAX + s) * M_;
#pragma unroll
        for (int k = 0; k < M_; ++k) {
            cand_idx[base + k] = tix[M_ - 1 - k];
            cand_val[base + k] = tv[M_ - 1 - k];
        }
    }
}

// ---------------- Kernel 3: segment merge + fp64 refine + gather + gate epilogue ----------------
__global__ __launch_bounds__(256) void epi_kernel(const float* __restrict__ x,
                                                  const double* __restrict__ rn64,
                                                  const int* __restrict__ cand_idx,
                                                  const float* __restrict__ cand_val,
                                                  const float* __restrict__ gain,
                                                  const float* __restrict__ bias,
                                                  const float* __restrict__ lmix,
                                                  const float* __restrict__ lscale,
                                                  float* __restrict__ out,
                                                  int SEGJT, int NSEGMAX, int SHIFT) {
    const int row = blockIdx.x;           // b*T + i
    const int b   = row >> 12;
    const int i   = row & (T_ - 1);
    const int tid = threadIdx.x;
    const int njt  = (i >> SHIFT) + 1;
    const int nseg = (njt + SEGJT - 1) / SEGJT;
    const int ncand = nseg * M_;          // <= 192

    __shared__ float  s_val[M_];
    __shared__ int    s_idx[M_];
    __shared__ int    s_sel[K_];
    __shared__ int    s_cnt;
    __shared__ double s_red[M_ * 4];
    __shared__ double s_sim[M_];

    // wave-0 parallel merge: 64 lanes x up to 3 candidates, 12 argmax rounds
    if (tid < 64) {
        const size_t cb = (size_t)row * NSEGMAX * M_;
        float v0 = -INFINITY, v1 = -INFINITY, v2 = -INFINITY;
        int   x0 = -1, x1 = -1, x2 = -1;
        if (tid < ncand)       { v0 = cand_val[cb + tid];       x0 = cand_idx[cb + tid]; }
        if (tid + 64 < ncand)  { v1 = cand_val[cb + tid + 64];  x1 = cand_idx[cb + tid + 64]; }
        if (tid + 128 < ncand) { v2 = cand_val[cb + tid + 128]; x2 = cand_idx[cb + tid + 128]; }
        if (x0 < 0) v0 = -INFINITY;
        if (x1 < 0) v1 = -INFINITY;
        if (x2 < 0) v2 = -INFINITY;
        // sort3 descending (ties -> lower idx)
        {
            bool sw;
            sw = (v1 > v0) || (v1 == v0 && (unsigned)x1 < (unsigned)x0);
            if (sw) { float tv = v0; v0 = v1; v1 = tv; int ti = x0; x0 = x1; x1 = ti; }
            sw = (v2 > v1) || (v2 == v1 && (unsigned)x2 < (unsigned)x1);
            if (sw) { float tv = v1; v1 = v2; v2 = tv; int ti = x1; x1 = x2; x2 = ti; }
            sw = (v1 > v0) || (v1 == v0 && (unsigned)x1 < (unsigned)x0);
            if (sw) { float tv = v0; v0 = v1; v1 = tv; int ti = x0; x0 = x1; x1 = ti; }
        }
#pragma unroll
        for (int r = 0; r < M_; ++r) {
            float bv = v0; int bi = x0;
#pragma unroll
            for (int o = 1; o < 64; o <<= 1) {
                const float ov = __shfl_xor(bv, o);
                const int   oi = __shfl_xor(bi, o);
                const bool take = (ov > bv) || (ov == bv && (unsigned)oi < (unsigned)bi);
                bv = take ? ov : bv; bi = take ? oi : bi;
            }
            if (v0 == bv && x0 == bi) { v0 = v1; x0 = x1; v1 = v2; x1 = x2; v2 = -INFINITY; x2 = -1; }
            if (tid == 0) { s_val[r] = bv; s_idx[r] = bi; }
        }
    }
    __syncthreads();

    int nvalid = 0;
#pragma unroll
    for (int k = 0; k < M_; ++k) nvalid += (s_idx[k] >= 0);
    const bool refine = (nvalid > K_) && (s_val[K_ - 1] - s_val[K_] < 2e-4f);

    const float4 xiv = reinterpret_cast<const float4*>(x + (size_t)row * D_)[tid];

    if (refine) {
        double pd[M_];
#pragma unroll
        for (int c = 0; c < M_; ++c) {
            pd[c] = 0.0;
            const int j = s_idx[c];
            if (j >= 0) {
                const float4 xc = reinterpret_cast<const float4*>(x + ((size_t)b * T_ + j) * D_)[tid];
                pd[c] = (double)xiv.x * xc.x + (double)xiv.y * xc.y +
                        (double)xiv.z * xc.z + (double)xiv.w * xc.w;
            }
        }
#pragma unroll
        for (int c = 0; c < M_; ++c) {
            double s = pd[c];
            for (int o = 32; o > 0; o >>= 1) s += __shfl_down(s, o);
            if ((tid & 63) == 0) s_red[c * 4 + (tid >> 6)] = s;
        }
        __syncthreads();
        if (tid < M_) {
            const double s = s_red[tid * 4] + s_red[tid * 4 + 1] +
                             s_red[tid * 4 + 2] + s_red[tid * 4 + 3];
            const int j = s_idx[tid];
            s_sim[tid] = (j >= 0) ? s * rn64[row] * rn64[b * T_ + j] : -INFINITY;
        }
        __syncthreads();
        if (tid == 0) {
            bool taken[M_];
#pragma unroll
            for (int c = 0; c < M_; ++c) taken[c] = false;
            int cnt = 0;
            for (int k = 0; k < K_; ++k) {
                int best = -1, bidx = 0x7fffffff;
                double bv = -1e300;
                for (int c = 0; c < M_; ++c) {
                    if (taken[c] || s_idx[c] < 0) continue;
                    const double v = s_sim[c];
                    if (v > bv || (v == bv && s_idx[c] < bidx)) { bv = v; best = c; bidx = s_idx[c]; }
                }
                if (best >= 0) { taken[best] = true; s_sel[k] = s_idx[best]; ++cnt; }
                else s_sel[k] = -1;
            }
            s_cnt = cnt > 0 ? cnt : 1;
        }
    } else {
        if (tid == 0) {
            int cnt = 0;
            for (int k = 0; k < K_; ++k) { const int j = s_idx[k]; s_sel[k] = j; cnt += (j >= 0); }
            s_cnt = cnt > 0 ? cnt : 1;
        }
    }
    __syncthreads();

    float mx = 0.f, my = 0.f, mz = 0.f, mw = 0.f;
#pragma unroll
    for (int k = 0; k < K_; ++k) {
        const int j = s_sel[k];
        if (j >= 0) {
            const float4 xc = reinterpret_cast<const float4*>(x + ((size_t)b * T_ + j) * D_)[tid];
            mx += xc.x; my += xc.y; mz += xc.z; mw += xc.w;
        }
    }
    const float inv = 1.0f / (float)s_cnt;
    const float lm = lmix[0], ls = lscale[0];
    const float mix = 1.0f / (1.0f + expf(-lm));
    const float sc  = (fmaxf(ls, 0.f) + log1pf(expf(-fabsf(ls)))) + 0.01f;
    const float4 g  = reinterpret_cast<const float4*>(gain)[tid];
    const float4 bb = reinterpret_cast<const float4*>(bias)[tid];

    float4 o4;
    {
        float m, bl, y;
        m = mx * inv; bl = mix * xiv.x + (1.f - mix) * m; y = bl * g.x + bb.x;
        o4.x = 0.5f * y * (1.f + erff(y * 0.70710678118654752f)) * sc;
        m = my * inv; bl = mix * xiv.y + (1.f - mix) * m; y = bl * g.y + bb.y;
        o4.y = 0.5f * y * (1.f + erff(y * 0.70710678118654752f)) * sc;
        m = mz * inv; bl = mix * xiv.z + (1.f - mix) * m; y = bl * g.z + bb.z;
        o4.z = 0.5f * y * (1.f + erff(y * 0.70710678118654752f)) * sc;
        m = mw * inv; bl = mix * xiv.w + (1.f - mix) * m; y = bl * g.w + bb.w;
        o4.w = 0.5f * y * (1.f + erff(y * 0.70710678118654752f)) * sc;
    }
    reinterpret_cast<float4*>(out + (size_t)row * D_)[tid] = o4;
}

// ---------------- launch ----------------
extern "C" void kernel_launch(void* const* d_in, const int* in_sizes, int n_in,
                              void* d_out, int out_size, void* d_ws, size_t ws_size,
                              hipStream_t stream) {
    const float* x      = (const float*)d_in[0];
    const float* gain   = (const float*)d_in[1];
    const float* bias   = (const float*)d_in[2];
    const float* lmix   = (const float*)d_in[3];
    const float* lscale = (const float*)d_in[4];
    float* out = (float*)d_out;

    char* ws = (char*)d_ws;
    float*  rn32 = (float*)ws;                       // 64 KB
    double* rn64 = (double*)(ws + 65536);            // 128 KB
    const size_t HL = (size_t)B_ * T_ * D_ * 2;      // 33554432 bytes per bf16 array
    unsigned short* xh = (unsigned short*)(ws + 196608);
    unsigned short* xl = (unsigned short*)(ws + 196608 + HL);
    const size_t base_mfma = 196608 + 2 * HL;

    auto candBytes = [](int nseg) { return (size_t)B_ * T_ * nseg * M_ * 8; };

    int SEGJT = 0, NSEG = 0; bool use_mfma = false;
    if      (ws_size >= base_mfma + candBytes(16)) { use_mfma = true; SEGJT = 1;  NSEG = 16; }
    else if (ws_size >= base_mfma + candBytes(8))  { use_mfma = true; SEGJT = 2;  NSEG = 8;  }
    else if (ws_size >= base_mfma + candBytes(4))  { use_mfma = true; SEGJT = 4;  NSEG = 4;  }
    else if (ws_size >= base_mfma + candBytes(1))  { use_mfma = true; SEGJT = 16; NSEG = 1;  }

    if (use_mfma) {
        int*   cidx = (int*)(ws + base_mfma);
        float* cval = (float*)(ws + base_mfma + candBytes(NSEG) / 2);
        norm_prep_kernel<<<dim3(B_ * T_), dim3(256), 0, stream>>>(x, rn32, rn64, xh, xl, 1);
        (void)hipFuncSetAttribute((const void*)simtopk_mfma,
                                  hipFuncAttributeMaxDynamicSharedMemorySize, 81920);
        simtopk_mfma<<<dim3(B_ * 64 * NSEG), dim3(256), 81920, stream>>>(
            xh, xl, cidx, cval, SEGJT, NSEG);
        epi_kernel<<<dim3(B_ * T_), dim3(256), 0, stream>>>(x, rn64, cidx, cval,
                                                            gain, bias, lmix, lscale, out,
                                                            SEGJT, NSEG, 8);
    } else {
        int SEG2, NSEG2;
        if (ws_size >= 196608 + candBytes(9)) { SEG2 = 4;  NSEG2 = 9; }
        else                                  { SEG2 = 33; NSEG2 = 1; }
        int*   cidx = (int*)(ws + 196608);
        float* cval = (float*)(ws + 196608 + candBytes(NSEG2) / 2);
        norm_prep_kernel<<<dim3(B_ * T_), dim3(256), 0, stream>>>(x, rn32, rn64, nullptr, nullptr, 0);
        simtopk_fp32<<<dim3(B_ * 128 * NSEG2), dim3(256), 0, stream>>>(x, rn32, cidx, cval, SEG2, NSEG2);
        epi_kernel<<<dim3(B_ * T_), dim3(256), 0, stream>>>(x, rn64, cidx, cval,
                                                            gain, bias, lmix, lscale, out,
                                                            SEG2, NSEG2, 7);
    }
}

// Round 4
// 848.344 us; speedup vs baseline: 3.2502x; 1.7560x over previous
//
#include <hip/hip_runtime.h>
#include <math.h>

#define B_ 4
#define T_ 4096
#define D_ 1024
#define K_ 8
#define M_ 12          // candidates kept per row/segment (refined to top-K)

// fallback fp32-path tile params
#define BI 32
#define BJ 128
#define DC 32

typedef __attribute__((ext_vector_type(8))) short bf16x8;
typedef __attribute__((ext_vector_type(16))) float f32x16;

// branch-free sorted insert into ascending top-12 (tv[0]=min). Static indices.
__device__ __forceinline__ void ins12(float (&tv)[M_], int (&tix)[M_], float v, int nj) {
#pragma unroll
    for (int k = 0; k < M_; ++k) {
        const float nxt = (k < M_ - 1) ? tv[k + 1] : INFINITY;
        const int   nxi = (k < M_ - 1) ? tix[k + 1] : -1;
        const bool  up  = v > nxt;
        const bool  mid = v > tv[k];
        tv[k]  = up ? nxt : (mid ? v  : tv[k]);
        tix[k] = up ? nxi : (mid ? nj : tix[k]);
    }
}

__device__ __forceinline__ unsigned short f2bf_rne(float f) {
    unsigned u = __float_as_uint(f);
    unsigned r = (u + 0x7FFFu + ((u >> 16) & 1u)) >> 16;
    return (unsigned short)r;
}

// ---------------- Kernel 1: row norms (fp64 truth) + optional bf16 hi/lo prep ----------------
__global__ __launch_bounds__(256) void norm_prep_kernel(const float* __restrict__ x,
                                                        float* __restrict__ rn32,
                                                        double* __restrict__ rn64,
                                                        unsigned short* __restrict__ xh,
                                                        unsigned short* __restrict__ xl,
                                                        int do_prep) {
    const int row = blockIdx.x;
    const int tid = threadIdx.x;
    const float4 v = reinterpret_cast<const float4*>(x + (size_t)row * D_)[tid];
    double ss = (double)v.x * v.x + (double)v.y * v.y +
                (double)v.z * v.z + (double)v.w * v.w;
    for (int o = 32; o > 0; o >>= 1) ss += __shfl_down(ss, o);
    __shared__ double ws[4];
    __shared__ double s_rn;
    if ((tid & 63) == 0) ws[tid >> 6] = ss;
    __syncthreads();
    if (tid == 0) {
        double s = ws[0] + ws[1] + ws[2] + ws[3];
        double rn = 1.0 / (sqrt(s) + 1e-8);
        rn64[row] = rn;
        rn32[row] = (float)rn;
        s_rn = rn;
    }
    __syncthreads();
    if (do_prep) {
        const float rnf = (float)s_rn;
        float vn[4] = {v.x * rnf, v.y * rnf, v.z * rnf, v.w * rnf};
        ushort4 h, l;
        unsigned short* hp = &h.x; unsigned short* lp = &l.x;
#pragma unroll
        for (int e = 0; e < 4; ++e) {
            unsigned short hb = f2bf_rne(vn[e]);
            float hf = __uint_as_float(((unsigned)hb) << 16);
            hp[e] = hb;
            lp[e] = f2bf_rne(vn[e] - hf);
        }
        reinterpret_cast<ushort4*>(xh + (size_t)row * D_)[tid] = h;
        reinterpret_cast<ushort4*>(xl + (size_t)row * D_)[tid] = l;
    }
}

// ---------------- Kernel 2a: MFMA hi/lo similarity + per-segment top-M ----------------
__global__ __launch_bounds__(256, 2) void simtopk_mfma(const unsigned short* __restrict__ xh,
                                                       const unsigned short* __restrict__ xl,
                                                       int* __restrict__ cand_idx,
                                                       float* __restrict__ cand_val,
                                                       int SEGJT, int NSEGMAX) {
    extern __shared__ char sm[];
    const int bid = blockIdx.x;
    const int s   = bid % NSEGMAX;
    const int bt  = bid / NSEGMAX;
    const int t   = bt & 63;
    const int b   = bt >> 6;
    const int njt = (t >> 2) + 1;
    const int jt0 = s * SEGJT;
    if (jt0 >= njt) return;
    const int jt1 = min(jt0 + SEGJT, njt);
    const int i0  = t << 6;

    const int tid  = threadIdx.x;
    const int lane = tid & 63;
    const int wc   = tid >> 6;
    const int l31  = lane & 31;
    const int lhi  = lane >> 5;

    const unsigned short* xhb = xh + (size_t)b * T_ * D_;
    const unsigned short* xlb = xl + (size_t)b * T_ * D_;

    char* Ah = sm;
    char* Al = sm + 8192;
    char* Bh = sm + 16384;
    char* Bl = sm + 49152;
    float* Sf = (float*)sm;

    const int srow = tid >> 2;
    const int stc  = tid & 3;
    const int gi   = i0 + srow;
    const int r7   = srow & 7;

    float tv[M_]; int tix[M_];
#pragma unroll
    for (int k = 0; k < M_; ++k) { tv[k] = -INFINITY; tix[k] = -1; }

    for (int jt = jt0; jt < jt1; ++jt) {
        const int j0 = jt << 8;
        f32x16 acc[2][2];
#pragma unroll
        for (int m = 0; m < 2; ++m)
#pragma unroll
            for (int n = 0; n < 2; ++n)
#pragma unroll
                for (int r = 0; r < 16; ++r) acc[m][n][r] = 0.f;

        for (int dc = 0; dc < D_; dc += 64) {
            __syncthreads();
#pragma unroll
            for (int it = 0; it < 2; ++it) {
                const int g   = tid + (it << 8);
                const int row = g >> 3, kg = g & 7;
                const size_t ga = (size_t)(i0 + row) * D_ + dc + (kg << 3);
                const uint4 vh = *reinterpret_cast<const uint4*>(xhb + ga);
                const uint4 vl = *reinterpret_cast<const uint4*>(xlb + ga);
                const int off = row * 128 + ((kg ^ (row & 7)) << 4);
                *reinterpret_cast<uint4*>(Ah + off) = vh;
                *reinterpret_cast<uint4*>(Al + off) = vl;
            }
#pragma unroll
            for (int it = 0; it < 8; ++it) {
                const int g   = tid + (it << 8);
                const int row = g >> 3, kg = g & 7;
                const size_t ga = (size_t)(j0 + row) * D_ + dc + (kg << 3);
                const uint4 vh = *reinterpret_cast<const uint4*>(xhb + ga);
                const uint4 vl = *reinterpret_cast<const uint4*>(xlb + ga);
                const int off = row * 128 + ((kg ^ (row & 7)) << 4);
                *reinterpret_cast<uint4*>(Bh + off) = vh;
                *reinterpret_cast<uint4*>(Bl + off) = vl;
            }
            __syncthreads();
#pragma unroll
            for (int ks = 0; ks < 4; ++ks) {
                const int kg = (ks << 1) + lhi;
                bf16x8 ah[2], al2[2], bh2[2], bl2[2];
#pragma unroll
                for (int m = 0; m < 2; ++m) {
                    const int row = (m << 5) + l31;
                    const int off = row * 128 + ((kg ^ (row & 7)) << 4);
                    ah[m]  = *reinterpret_cast<bf16x8*>(Ah + off);
                    al2[m] = *reinterpret_cast<bf16x8*>(Al + off);
                }
#pragma unroll
                for (int n = 0; n < 2; ++n) {
                    const int row = (wc << 6) + (n << 5) + l31;
                    const int off = row * 128 + ((kg ^ (row & 7)) << 4);
                    bh2[n] = *reinterpret_cast<bf16x8*>(Bh + off);
                    bl2[n] = *reinterpret_cast<bf16x8*>(Bl + off);
                }
#pragma unroll
                for (int m = 0; m < 2; ++m)
#pragma unroll
                    for (int n = 0; n < 2; ++n) {
                        acc[m][n] = __builtin_amdgcn_mfma_f32_32x32x16_bf16(ah[m],  bh2[n], acc[m][n], 0, 0, 0);
                        acc[m][n] = __builtin_amdgcn_mfma_f32_32x32x16_bf16(ah[m],  bl2[n], acc[m][n], 0, 0, 0);
                        acc[m][n] = __builtin_amdgcn_mfma_f32_32x32x16_bf16(al2[m], bh2[n], acc[m][n], 0, 0, 0);
                    }
            }
        }
        __syncthreads();
#pragma unroll
        for (int m = 0; m < 2; ++m)
#pragma unroll
            for (int n = 0; n < 2; ++n)
#pragma unroll
                for (int r = 0; r < 16; ++r) {
                    const int row = (m << 5) + (r & 3) + ((r >> 2) << 3) + (lhi << 2);
                    const int col = (wc << 6) + (n << 5) + l31;
                    const int word = (row << 8) + ((((col >> 2) ^ (row & 7)) << 2) | (col & 3));
                    Sf[word] = acc[m][n][r];
                }
        __syncthreads();
#pragma unroll 2
        for (int c4 = 0; c4 < 16; ++c4) {
            const int fc4  = (stc << 4) | c4;
            const int word = (srow << 8) + ((fc4 ^ r7) << 2);
            const float4 v4 = *reinterpret_cast<float4*>(Sf + word);
            const int jb = j0 + (stc << 6) + (c4 << 2);
            const float a0 = (jb + 0 <= gi) ? v4.x : -INFINITY;
            const float a1 = (jb + 1 <= gi) ? v4.y : -INFINITY;
            const float a2 = (jb + 2 <= gi) ? v4.z : -INFINITY;
            const float a3 = (jb + 3 <= gi) ? v4.w : -INFINITY;
            const float mx = fmaxf(fmaxf(a0, a1), fmaxf(a2, a3));
            if (mx > tv[0]) {
                if (a0 > tv[0]) ins12(tv, tix, a0, jb + 0);
                if (a1 > tv[0]) ins12(tv, tix, a1, jb + 1);
                if (a2 > tv[0]) ins12(tv, tix, a2, jb + 2);
                if (a3 > tv[0]) ins12(tv, tix, a3, jb + 3);
            }
        }
    }
    __syncthreads();
    float* mv = (float*)sm;
    int*   mi = (int*)(sm + 12288);
    {
        const int base = (srow * 4 + stc) * M_;
#pragma unroll
        for (int k = 0; k < M_; ++k) { mv[base + k] = tv[k]; mi[base + k] = tix[k]; }
    }
    __syncthreads();
    if (stc == 0) {
        float gv[M_]; int gx[M_];
#pragma unroll
        for (int k = 0; k < M_; ++k) { gv[k] = -INFINITY; gx[k] = -1; }
        for (int sc = 0; sc < 4; ++sc) {
            const int base = (srow * 4 + sc) * M_;
            for (int k = M_ - 1; k >= 0; --k) {
                const float v = mv[base + k];
                if (!(v > gv[0])) break;
                const int nj = mi[base + k];
                if (nj >= 0) ins12(gv, gx, v, nj);
            }
        }
        const size_t cb = ((size_t)(b * T_ + gi) * NSEGMAX + s) * M_;
#pragma unroll
        for (int k = 0; k < M_; ++k) {
            cand_val[cb + k] = gv[M_ - 1 - k];
            cand_idx[cb + k] = gx[M_ - 1 - k];
        }
    }
}

// ---------------- Kernel 2b: fp32 fallback ----------------
__global__ __launch_bounds__(256) void simtopk_fp32(const float* __restrict__ x,
                                                    const float* __restrict__ rn32,
                                                    int* __restrict__ cand_idx,
                                                    float* __restrict__ cand_val,
                                                    int SEGJT, int NSEGMAX) {
    __shared__ __align__(16) float smem[DC * 36 + DC * 132];
    float (*At)[36]  = reinterpret_cast<float(*)[36]>(smem);
    float (*Bt)[132] = reinterpret_cast<float(*)[132]>(smem + DC * 36);
    float (*Cs)[132] = reinterpret_cast<float(*)[132]>(smem);

    const int bid = blockIdx.x;
    const int s   = bid % NSEGMAX;
    const int bt  = bid / NSEGMAX;
    const int t   = bt & 127;
    const int b   = bt >> 7;
    const int njt = (t >> 2) + 1;
    const int jt0 = s * SEGJT;
    if (jt0 >= njt) return;
    const int jt1 = min(jt0 + SEGJT, njt);
    const int i0  = t * BI;

    const int tid = threadIdx.x;
    const int tx  = tid & 31;
    const int ty  = tid >> 5;
    const float* xb = x + (size_t)b * T_ * D_;
    const float* rb = rn32 + b * T_;

    const int ai  = tid >> 3;
    const int adq = (tid & 7) << 2;

    float tv[M_]; int tix[M_];
#pragma unroll
    for (int k = 0; k < M_; ++k) { tv[k] = -INFINITY; tix[k] = -1; }

    for (int jt = jt0; jt < jt1; ++jt) {
        const int j0 = jt << 7;
        float acc[4][4];
#pragma unroll
        for (int ii = 0; ii < 4; ++ii)
#pragma unroll
            for (int jj = 0; jj < 4; ++jj) acc[ii][jj] = 0.f;

        for (int dc = 0; dc < D_; dc += DC) {
            __syncthreads();
            {
                const float rn = rb[i0 + ai];
                float4 v = *reinterpret_cast<const float4*>(&xb[(size_t)(i0 + ai) * D_ + dc + adq]);
                At[adq + 0][ai] = v.x * rn;
                At[adq + 1][ai] = v.y * rn;
                At[adq + 2][ai] = v.z * rn;
                At[adq + 3][ai] = v.w * rn;
            }
#pragma unroll
            for (int l = 0; l < 4; ++l) {
                const int li = tid + (l << 8);
                const int j  = li >> 3;
                const int dq = (li & 7) << 2;
                const float rn = rb[j0 + j];
                float4 v = *reinterpret_cast<const float4*>(&xb[(size_t)(j0 + j) * D_ + dc + dq]);
                Bt[dq + 0][j] = v.x * rn;
                Bt[dq + 1][j] = v.y * rn;
                Bt[dq + 2][j] = v.z * rn;
                Bt[dq + 3][j] = v.w * rn;
            }
            __syncthreads();
#pragma unroll 8
            for (int d = 0; d < DC; ++d) {
                float4 a  = *reinterpret_cast<const float4*>(&At[d][ty << 2]);
                float4 bv = *reinterpret_cast<const float4*>(&Bt[d][tx << 2]);
                float av[4] = {a.x, a.y, a.z, a.w};
                float bw[4] = {bv.x, bv.y, bv.z, bv.w};
#pragma unroll
                for (int ii = 0; ii < 4; ++ii)
#pragma unroll
                    for (int jj = 0; jj < 4; ++jj)
                        acc[ii][jj] = fmaf(av[ii], bw[jj], acc[ii][jj]);
            }
        }
        __syncthreads();
#pragma unroll
        for (int ii = 0; ii < 4; ++ii) {
            *reinterpret_cast<float4*>(&Cs[(ty << 2) + ii][tx << 2]) =
                make_float4(acc[ii][0], acc[ii][1], acc[ii][2], acc[ii][3]);
        }
        __syncthreads();
        if (tid < BI) {
            const int gi   = i0 + tid;
            const int jmax = gi - j0;
            const int cend = jmax < BJ - 1 ? jmax : BJ - 1;
            for (int c = 0; c <= cend; ++c) {
                const float v = Cs[tid][c];
                if (v > tv[0]) ins12(tv, tix, v, j0 + c);
            }
        }
    }
    if (tid < BI) {
        const size_t base = ((size_t)(b * T_ + i0 + tid) * NSEGMAX + s) * M_;
#pragma unroll
        for (int k = 0; k < M_; ++k) {
            cand_idx[base + k] = tix[M_ - 1 - k];
            cand_val[base + k] = tv[M_ - 1 - k];
        }
    }
}

// ---------------- Kernel 3a: wave-per-row rank-merge + fp64 refine -> sel[] ----------------
// Block = 256 thr = 4 independent waves; wave handles one row. No divergent barriers.
__global__ __launch_bounds__(256) void select_kernel(const float* __restrict__ x,
                                                     const double* __restrict__ rn64,
                                                     const int* __restrict__ cand_idx,
                                                     const float* __restrict__ cand_val,
                                                     int* __restrict__ sel,
                                                     int SEGJT, int NSEGMAX, int SHIFT) {
    const int tid  = threadIdx.x;
    const int wid  = tid >> 6;
    const int lane = tid & 63;
    const int row  = (blockIdx.x << 2) + wid;
    const int b    = row >> 12;
    const int i    = row & (T_ - 1);
    const int njt  = (i >> SHIFT) + 1;
    const int nseg = (njt + SEGJT - 1) / SEGJT;
    const int ncand = nseg * M_;              // <= 192

    __shared__ unsigned long long keys[4][192];
    __shared__ float v12[4][12];
    __shared__ int   i12[4][12];

    if (lane < 12) { v12[wid][lane] = -INFINITY; i12[wid][lane] = -1; }

    const size_t cb = (size_t)row * NSEGMAX * M_;
    float cv[3]; int cj[3]; unsigned long long kk[3];
#pragma unroll
    for (int q = 0; q < 3; ++q) {
        const int c = lane + (q << 6);
        if (c < ncand) { cv[q] = cand_val[cb + c]; cj[q] = cand_idx[cb + c]; }
        else           { cv[q] = -INFINITY;        cj[q] = -1; }
        unsigned u = __float_as_uint(cv[q]);
        unsigned so = (u & 0x80000000u) ? ~u : (u | 0x80000000u);
        kk[q] = (cj[q] >= 0)
              ? ((((unsigned long long)so) << 32) | (unsigned long long)(0xFFFFFFFFu - (unsigned)cj[q]))
              : 0ull;
        keys[wid][lane + (q << 6)] = kk[q];
    }
    int nv = 0;
#pragma unroll
    for (int q = 0; q < 3; ++q) nv += __popcll(__ballot(cj[q] >= 0));
    __syncthreads();                           // (1) keys visible block-wide

    int rk0 = 0, rk1 = 0, rk2 = 0;
#pragma unroll 4
    for (int c = 0; c < ncand; ++c) {
        const unsigned long long kc = keys[wid][c];
        rk0 += (kc > kk[0]);
        rk1 += (kc > kk[1]);
        rk2 += (kc > kk[2]);
    }
    if (cj[0] >= 0 && rk0 < 12) { v12[wid][rk0] = cv[0]; i12[wid][rk0] = cj[0]; }
    if (cj[1] >= 0 && rk1 < 12) { v12[wid][rk1] = cv[1]; i12[wid][rk1] = cj[1]; }
    if (cj[2] >= 0 && rk2 < 12) { v12[wid][rk2] = cv[2]; i12[wid][rk2] = cj[2]; }
    __syncthreads();                           // (2) v12/i12 placed

    const float v8 = v12[wid][7];
    const float v9 = v12[wid][8];
    const bool refine = (nv > K_) && (v8 - v9 < 2e-4f);   // wave-uniform

    int outj = -1;
    int cnt;
    if (refine) {
        const float* xi = x + (size_t)row * D_;
        float4 xa[4];
#pragma unroll
        for (int q = 0; q < 4; ++q)
            xa[q] = *reinterpret_cast<const float4*>(xi + (lane << 4) + (q << 2));
        double sim[12]; int jj[12];
#pragma unroll
        for (int c = 0; c < 12; ++c) {
            const int j = i12[wid][c];
            jj[c] = j;
            double s = 0.0;
            if (j >= 0) {
                const float* xj = x + ((size_t)(b << 12) + j) * D_;
#pragma unroll
                for (int q = 0; q < 4; ++q) {
                    const float4 xc = *reinterpret_cast<const float4*>(xj + (lane << 4) + (q << 2));
                    s += (double)xa[q].x * xc.x + (double)xa[q].y * xc.y +
                         (double)xa[q].z * xc.z + (double)xa[q].w * xc.w;
                }
            }
            sim[c] = s;
        }
#pragma unroll
        for (int c = 0; c < 12; ++c) {
#pragma unroll
            for (int o = 1; o < 64; o <<= 1) sim[c] += __shfl_xor(sim[c], o);
        }
        const double rni = rn64[row];
#pragma unroll
        for (int c = 0; c < 12; ++c)
            sim[c] = (jj[c] >= 0) ? sim[c] * rni * rn64[(b << 12) + jj[c]] : -1e300;
        // every lane computes the top-8 set (by sim desc, idx asc) in registers
        unsigned msel = 0;
#pragma unroll
        for (int c = 0; c < 12; ++c) {
            int r = 0;
#pragma unroll
            for (int d = 0; d < 12; ++d) {
                if (d == c) continue;
                r += (sim[d] > sim[c]) || (sim[d] == sim[c] && jj[d] < jj[c]);
            }
            if (jj[c] >= 0 && r < 8) msel |= (1u << c);
        }
        cnt = __popc(msel); if (cnt < 1) cnt = 1;
        if (lane < 8) {
            int seen = 0;
#pragma unroll
            for (int c = 0; c < 12; ++c) {
                if (msel & (1u << c)) { if (seen == lane) outj = jj[c]; ++seen; }
            }
        }
    } else {
        cnt = nv < K_ ? nv : K_; if (cnt < 1) cnt = 1;
        if (lane < 8) outj = i12[wid][lane];
    }
    if (lane < 8) sel[(row << 4) + lane] = outj;
    if (lane == 8) sel[(row << 4) + 8] = cnt;
}

// ---------------- Kernel 3b: streaming gather + gate epilogue ----------------
__global__ __launch_bounds__(256) void gather_kernel(const float* __restrict__ x,
                                                     const int* __restrict__ sel,
                                                     const float* __restrict__ gain,
                                                     const float* __restrict__ bias,
                                                     const float* __restrict__ lmix,
                                                     const float* __restrict__ lscale,
                                                     float* __restrict__ out) {
    const int row = blockIdx.x;
    const int b   = row >> 12;
    const int tid = threadIdx.x;
    const int sb  = row << 4;

    int js[8];
#pragma unroll
    for (int k = 0; k < 8; ++k) js[k] = sel[sb + k];
    const int cnt = sel[sb + 8];

    const float4 xiv = reinterpret_cast<const float4*>(x + (size_t)row * D_)[tid];
    float mx = 0.f, my = 0.f, mz = 0.f, mw = 0.f;
#pragma unroll
    for (int k = 0; k < 8; ++k) {
        const int j = js[k];
        if (j >= 0) {
            const float4 xc = reinterpret_cast<const float4*>(
                x + ((size_t)(b << 12) + j) * D_)[tid];
            mx += xc.x; my += xc.y; mz += xc.z; mw += xc.w;
        }
    }
    const float inv = 1.0f / (float)cnt;
    const float lm = lmix[0], ls = lscale[0];
    const float mix = 1.0f / (1.0f + expf(-lm));
    const float sc  = (fmaxf(ls, 0.f) + log1pf(expf(-fabsf(ls)))) + 0.01f;
    const float4 g  = reinterpret_cast<const float4*>(gain)[tid];
    const float4 bb = reinterpret_cast<const float4*>(bias)[tid];

    float4 o4;
    {
        float m, bl, y;
        m = mx * inv; bl = mix * xiv.x + (1.f - mix) * m; y = bl * g.x + bb.x;
        o4.x = 0.5f * y * (1.f + erff(y * 0.70710678118654752f)) * sc;
        m = my * inv; bl = mix * xiv.y + (1.f - mix) * m; y = bl * g.y + bb.y;
        o4.y = 0.5f * y * (1.f + erff(y * 0.70710678118654752f)) * sc;
        m = mz * inv; bl = mix * xiv.z + (1.f - mix) * m; y = bl * g.z + bb.z;
        o4.z = 0.5f * y * (1.f + erff(y * 0.70710678118654752f)) * sc;
        m = mw * inv; bl = mix * xiv.w + (1.f - mix) * m; y = bl * g.w + bb.w;
        o4.w = 0.5f * y * (1.f + erff(y * 0.70710678118654752f)) * sc;
    }
    reinterpret_cast<float4*>(out + (size_t)row * D_)[tid] = o4;
}

// ---------------- launch ----------------
extern "C" void kernel_launch(void* const* d_in, const int* in_sizes, int n_in,
                              void* d_out, int out_size, void* d_ws, size_t ws_size,
                              hipStream_t stream) {
    const float* x      = (const float*)d_in[0];
    const float* gain   = (const float*)d_in[1];
    const float* bias   = (const float*)d_in[2];
    const float* lmix   = (const float*)d_in[3];
    const float* lscale = (const float*)d_in[4];
    float* out = (float*)d_out;

    char* ws = (char*)d_ws;
    float*  rn32 = (float*)ws;                        // 64 KB
    double* rn64 = (double*)(ws + 65536);             // 128 KB
    int*    selb = (int*)(ws + 196608);               // B*T*16 ints = 1 MB
    const size_t base2 = 196608 + (size_t)B_ * T_ * 16 * 4;
    const size_t HL = (size_t)B_ * T_ * D_ * 2;       // 32 MB per bf16 array
    unsigned short* xh = (unsigned short*)(ws + base2);
    unsigned short* xl = (unsigned short*)(ws + base2 + HL);
    const size_t base_mfma = base2 + 2 * HL;

    auto candBytes = [](int nseg) { return (size_t)B_ * T_ * nseg * M_ * 8; };

    int SEGJT = 0, NSEG = 0; bool use_mfma = false;
    if      (ws_size >= base_mfma + candBytes(16)) { use_mfma = true; SEGJT = 1;  NSEG = 16; }
    else if (ws_size >= base_mfma + candBytes(8))  { use_mfma = true; SEGJT = 2;  NSEG = 8;  }
    else if (ws_size >= base_mfma + candBytes(4))  { use_mfma = true; SEGJT = 4;  NSEG = 4;  }
    else if (ws_size >= base_mfma + candBytes(1))  { use_mfma = true; SEGJT = 16; NSEG = 1;  }

    if (use_mfma) {
        int*   cidx = (int*)(ws + base_mfma);
        float* cval = (float*)(ws + base_mfma + candBytes(NSEG) / 2);
        norm_prep_kernel<<<dim3(B_ * T_), dim3(256), 0, stream>>>(x, rn32, rn64, xh, xl, 1);
        (void)hipFuncSetAttribute((const void*)simtopk_mfma,
                                  hipFuncAttributeMaxDynamicSharedMemorySize, 81920);
        simtopk_mfma<<<dim3(B_ * 64 * NSEG), dim3(256), 81920, stream>>>(
            xh, xl, cidx, cval, SEGJT, NSEG);
        select_kernel<<<dim3(B_ * T_ / 4), dim3(256), 0, stream>>>(
            x, rn64, cidx, cval, selb, SEGJT, NSEG, 8);
    } else {
        int SEG2, NSEG2;
        if (ws_size >= base2 + candBytes(9)) { SEG2 = 4;  NSEG2 = 9; }
        else                                 { SEG2 = 33; NSEG2 = 1; }
        int*   cidx = (int*)(ws + base2);
        float* cval = (float*)(ws + base2 + candBytes(NSEG2) / 2);
        norm_prep_kernel<<<dim3(B_ * T_), dim3(256), 0, stream>>>(x, rn32, rn64, nullptr, nullptr, 0);
        simtopk_fp32<<<dim3(B_ * 128 * NSEG2), dim3(256), 0, stream>>>(x, rn32, cidx, cval, SEG2, NSEG2);
        select_kernel<<<dim3(B_ * T_ / 4), dim3(256), 0, stream>>>(
            x, rn64, cidx, cval, selb, SEG2, NSEG2, 7);
    }
    gather_kernel<<<dim3(B_ * T_), dim3(256), 0, stream>>>(
        x, selb, gain, bias, lmix, lscale, out);
}

// Round 5
// 688.185 us; speedup vs baseline: 4.0067x; 1.2327x over previous
//
#include <hip/hip_runtime.h>
#include <math.h>

#define B_ 4
#define T_ 4096
#define D_ 1024
#define K_ 8
#define M_ 12          // candidates kept per row/segment (refined to top-K)

// f16 MFMA path params
#define NSEG_F16 8     // segments of SEGJT_F16 j-tiles (256 wide) per 64-row i-tile
#define SEGJT_F16 2

// fallback fp32-path tile params
#define BI 32
#define BJ 128
#define DC 32

typedef __attribute__((ext_vector_type(8))) _Float16 f16x8;
typedef __attribute__((ext_vector_type(4))) _Float16 f16x4;
typedef __attribute__((ext_vector_type(16))) float f32x16;

// branch-free sorted insert into ascending top-12 (tv[0]=min). Static indices.
__device__ __forceinline__ void ins12(float (&tv)[M_], int (&tix)[M_], float v, int nj) {
#pragma unroll
    for (int k = 0; k < M_; ++k) {
        const float nxt = (k < M_ - 1) ? tv[k + 1] : INFINITY;
        const int   nxi = (k < M_ - 1) ? tix[k + 1] : -1;
        const bool  up  = v > nxt;
        const bool  mid = v > tv[k];
        tv[k]  = up ? nxt : (mid ? v  : tv[k]);
        tix[k] = up ? nxi : (mid ? nj : tix[k]);
    }
}

// ---------------- Kernel 1: row norms (fp64 truth) + fp16 normalized prep ----------------
__global__ __launch_bounds__(256) void norm_prep_kernel(const float* __restrict__ x,
                                                        float* __restrict__ rn32,
                                                        double* __restrict__ rn64,
                                                        _Float16* __restrict__ xh,
                                                        int do_prep) {
    const int row = blockIdx.x;
    const int tid = threadIdx.x;
    const float4 v = reinterpret_cast<const float4*>(x + (size_t)row * D_)[tid];
    double ss = (double)v.x * v.x + (double)v.y * v.y +
                (double)v.z * v.z + (double)v.w * v.w;
    for (int o = 32; o > 0; o >>= 1) ss += __shfl_down(ss, o);
    __shared__ double ws[4];
    __shared__ double s_rn;
    if ((tid & 63) == 0) ws[tid >> 6] = ss;
    __syncthreads();
    if (tid == 0) {
        double s = ws[0] + ws[1] + ws[2] + ws[3];
        double rn = 1.0 / (sqrt(s) + 1e-8);
        rn64[row] = rn;
        rn32[row] = (float)rn;
        s_rn = rn;
    }
    __syncthreads();
    if (do_prep) {
        const float rnf = (float)s_rn;
        f16x4 h;
        h[0] = (_Float16)(v.x * rnf);
        h[1] = (_Float16)(v.y * rnf);
        h[2] = (_Float16)(v.z * rnf);
        h[3] = (_Float16)(v.w * rnf);
        *reinterpret_cast<f16x4*>(xh + (size_t)row * D_ + (tid << 2)) = h;
    }
}

// ---------------- Kernel 2a: fp16 MFMA similarity, swapped operands, register top-M ----------------
// Block: 256 thr = 4 waves. i-tile 64 rows (block), j-tile 256 per step (wave w: j rows [64w,64w+64)).
// Computes S^T tiles: A-operand = x^_j (direct global), B-operand = x^_i (LDS, padded).
// C frag: col = lane&31 = i-local, rows = j per (reg, lane>>5) -> per-lane register scan.
__global__ __launch_bounds__(256, 2) void simtopk_f16(const _Float16* __restrict__ xh,
                                                      int* __restrict__ cand_idx,
                                                      float* __restrict__ cand_val) {
    __shared__ __align__(16) char smem[49152];   // stage: 64 x 528B (33.8KB) | merge: 2 x 24KB

    const int bid = blockIdx.x;
    const int s   = bid & (NSEG_F16 - 1);
    const int bt  = bid >> 3;                    // NSEG_F16 = 8
    const int t   = bt & 63;
    const int b   = bt >> 6;
    const int njt = (t >> 2) + 1;                // 256-wide j-tiles covering rows [64t, 64t+63]
    const int jt0 = s * SEGJT_F16;
    if (jt0 >= njt) return;
    const int jt1 = min(jt0 + SEGJT_F16, njt);
    const int i0  = t << 6;

    const int tid  = threadIdx.x;
    const int wid  = tid >> 6;
    const int lane = tid & 63;
    const int l31  = lane & 31;
    const int lhi  = lane >> 5;

    const _Float16* xb = xh + (size_t)b * T_ * D_;

    float tv0[M_], tv1[M_]; int tix0[M_], tix1[M_];
#pragma unroll
    for (int k = 0; k < M_; ++k) {
        tv0[k] = -INFINITY; tix0[k] = -1;
        tv1[k] = -INFINITY; tix1[k] = -1;
    }

    const int ia = i0 + l31;          // ni=0 column owned by this lane
    const int ib = ia + 32;           // ni=1 column

    for (int jt = jt0; jt < jt1; ++jt) {
        const int j0 = jt << 8;
        f32x16 acc00{}, acc01{}, acc10{}, acc11{};   // [mj][ni]
#pragma unroll
        for (int r = 0; r < 16; ++r) { acc00[r] = 0.f; acc01[r] = 0.f; acc10[r] = 0.f; acc11[r] = 0.f; }

        const _Float16* jrow = xb + (size_t)(j0 + (wid << 6) + l31) * D_;

        for (int kh = 0; kh < 4; ++kh) {             // k chunks of 256
            __syncthreads();
            // stage i-panel chunk: 64 rows x 256 k fp16, row stride 528B (33 x 16B -> conflict-free)
#pragma unroll
            for (int q = 0; q < 8; ++q) {
                const int cid = (q << 8) + tid;
                const int row = cid >> 5;            // 0..63
                const int c   = cid & 31;            // 16B chunk in row
                const uint4 v = *reinterpret_cast<const uint4*>(
                    xb + (size_t)(i0 + row) * D_ + (kh << 8) + (c << 3));
                *reinterpret_cast<uint4*>(smem + row * 528 + (c << 4)) = v;
            }
            __syncthreads();
            const int koff = (kh << 8) + (lhi << 3); // element offset for this lane's k-pack
#pragma unroll
            for (int ks = 0; ks < 16; ++ks) {
                const int ko = koff + (ks << 4);
                const f16x8 aj0 = *reinterpret_cast<const f16x8*>(jrow + ko);
                const f16x8 aj1 = *reinterpret_cast<const f16x8*>(jrow + (size_t)32 * D_ + ko);
                const f16x8 bi0 = *reinterpret_cast<const f16x8*>(smem + l31 * 528 + (ks << 5) + (lhi << 4));
                const f16x8 bi1 = *reinterpret_cast<const f16x8*>(smem + (l31 + 32) * 528 + (ks << 5) + (lhi << 4));
                acc00 = __builtin_amdgcn_mfma_f32_32x32x16_f16(aj0, bi0, acc00, 0, 0, 0);
                acc01 = __builtin_amdgcn_mfma_f32_32x32x16_f16(aj0, bi1, acc01, 0, 0, 0);
                acc10 = __builtin_amdgcn_mfma_f32_32x32x16_f16(aj1, bi0, acc10, 0, 0, 0);
                acc11 = __builtin_amdgcn_mfma_f32_32x32x16_f16(aj1, bi1, acc11, 0, 0, 0);
            }
        }
        // register scan: lane holds rows j = jb + (r&3)+8*(r>>2) for cols ia (ni=0) and ib (ni=1)
        const int jb = j0 + (wid << 6) + (lhi << 2);
#pragma unroll
        for (int r = 0; r < 16; ++r) {
            const int j  = jb + (r & 3) + ((r >> 2) << 3);
            const int j2 = j + 32;
            { const float v = acc00[r]; if (j  <= ia && v > tv0[0]) ins12(tv0, tix0, v, j);  }
            { const float v = acc01[r]; if (j  <= ib && v > tv1[0]) ins12(tv1, tix1, v, j);  }
            { const float v = acc10[r]; if (j2 <= ia && v > tv0[0]) ins12(tv0, tix0, v, j2); }
            { const float v = acc11[r]; if (j2 <= ib && v > tv1[0]) ins12(tv1, tix1, v, j2); }
        }
    }

    // merge 8 lists per column i (4 waves x lhi) via LDS [k][list][i]
    __syncthreads();
    float* mval = reinterpret_cast<float*>(smem);            // [12][8][64]
    int*   midx = reinterpret_cast<int*>(smem + 24576);      // [12][8][64]
    const int list = (wid << 1) | lhi;
#pragma unroll
    for (int k = 0; k < M_; ++k) {
        mval[((k << 3) + list) * 64 + l31]      = tv0[k];
        midx[((k << 3) + list) * 64 + l31]      = tix0[k];
        mval[((k << 3) + list) * 64 + 32 + l31] = tv1[k];
        midx[((k << 3) + list) * 64 + 32 + l31] = tix1[k];
    }
    __syncthreads();
    if (tid < 64) {
        float gv[M_]; int gx[M_];
#pragma unroll
        for (int k = 0; k < M_; ++k) { gv[k] = -INFINITY; gx[k] = -1; }
        for (int ls = 0; ls < 8; ++ls) {
            for (int k = M_ - 1; k >= 0; --k) {      // stored ascending; walk descending
                const float v = mval[((k << 3) + ls) * 64 + tid];
                if (!(v > gv[0])) break;
                const int nj = midx[((k << 3) + ls) * 64 + tid];
                if (nj >= 0) ins12(gv, gx, v, nj);
            }
        }
        const size_t cb = ((size_t)(b * T_ + i0 + tid) * NSEG_F16 + s) * M_;
#pragma unroll
        for (int k = 0; k < M_; ++k) {
            cand_val[cb + k] = gv[M_ - 1 - k];
            cand_idx[cb + k] = gx[M_ - 1 - k];
        }
    }
}

// ---------------- Kernel 2b: fp32 fallback (used only if workspace too small) ----------------
__global__ __launch_bounds__(256) void simtopk_fp32(const float* __restrict__ x,
                                                    const float* __restrict__ rn32,
                                                    int* __restrict__ cand_idx,
                                                    float* __restrict__ cand_val,
                                                    int SEGJT, int NSEGMAX) {
    __shared__ __align__(16) float smem[DC * 36 + DC * 132];
    float (*At)[36]  = reinterpret_cast<float(*)[36]>(smem);
    float (*Bt)[132] = reinterpret_cast<float(*)[132]>(smem + DC * 36);
    float (*Cs)[132] = reinterpret_cast<float(*)[132]>(smem);

    const int bid = blockIdx.x;
    const int s   = bid % NSEGMAX;
    const int bt  = bid / NSEGMAX;
    const int t   = bt & 127;
    const int b   = bt >> 7;
    const int njt = (t >> 2) + 1;
    const int jt0 = s * SEGJT;
    if (jt0 >= njt) return;
    const int jt1 = min(jt0 + SEGJT, njt);
    const int i0  = t * BI;

    const int tid = threadIdx.x;
    const int tx  = tid & 31;
    const int ty  = tid >> 5;
    const float* xb = x + (size_t)b * T_ * D_;
    const float* rb = rn32 + b * T_;

    const int ai  = tid >> 3;
    const int adq = (tid & 7) << 2;

    float tv[M_]; int tix[M_];
#pragma unroll
    for (int k = 0; k < M_; ++k) { tv[k] = -INFINITY; tix[k] = -1; }

    for (int jt = jt0; jt < jt1; ++jt) {
        const int j0 = jt << 7;
        float acc[4][4];
#pragma unroll
        for (int ii = 0; ii < 4; ++ii)
#pragma unroll
            for (int jj = 0; jj < 4; ++jj) acc[ii][jj] = 0.f;

        for (int dc = 0; dc < D_; dc += DC) {
            __syncthreads();
            {
                const float rn = rb[i0 + ai];
                float4 v = *reinterpret_cast<const float4*>(&xb[(size_t)(i0 + ai) * D_ + dc + adq]);
                At[adq + 0][ai] = v.x * rn;
                At[adq + 1][ai] = v.y * rn;
                At[adq + 2][ai] = v.z * rn;
                At[adq + 3][ai] = v.w * rn;
            }
#pragma unroll
            for (int l = 0; l < 4; ++l) {
                const int li = tid + (l << 8);
                const int j  = li >> 3;
                const int dq = (li & 7) << 2;
                const float rn = rb[j0 + j];
                float4 v = *reinterpret_cast<const float4*>(&xb[(size_t)(j0 + j) * D_ + dc + dq]);
                Bt[dq + 0][j] = v.x * rn;
                Bt[dq + 1][j] = v.y * rn;
                Bt[dq + 2][j] = v.z * rn;
                Bt[dq + 3][j] = v.w * rn;
            }
            __syncthreads();
#pragma unroll 8
            for (int d = 0; d < DC; ++d) {
                float4 a  = *reinterpret_cast<const float4*>(&At[d][ty << 2]);
                float4 bv = *reinterpret_cast<const float4*>(&Bt[d][tx << 2]);
                float av[4] = {a.x, a.y, a.z, a.w};
                float bw[4] = {bv.x, bv.y, bv.z, bv.w};
#pragma unroll
                for (int ii = 0; ii < 4; ++ii)
#pragma unroll
                    for (int jj = 0; jj < 4; ++jj)
                        acc[ii][jj] = fmaf(av[ii], bw[jj], acc[ii][jj]);
            }
        }
        __syncthreads();
#pragma unroll
        for (int ii = 0; ii < 4; ++ii) {
            *reinterpret_cast<float4*>(&Cs[(ty << 2) + ii][tx << 2]) =
                make_float4(acc[ii][0], acc[ii][1], acc[ii][2], acc[ii][3]);
        }
        __syncthreads();
        if (tid < BI) {
            const int gi   = i0 + tid;
            const int jmax = gi - j0;
            const int cend = jmax < BJ - 1 ? jmax : BJ - 1;
            for (int c = 0; c <= cend; ++c) {
                const float v = Cs[tid][c];
                if (v > tv[0]) ins12(tv, tix, v, j0 + c);
            }
        }
    }
    if (tid < BI) {
        const size_t base = ((size_t)(b * T_ + i0 + tid) * NSEGMAX + s) * M_;
#pragma unroll
        for (int k = 0; k < M_; ++k) {
            cand_idx[base + k] = tix[M_ - 1 - k];
            cand_val[base + k] = tv[M_ - 1 - k];
        }
    }
}

// ---------------- Kernel 3a: wave-per-row rank-merge + fp64 refine -> sel[] ----------------
__global__ __launch_bounds__(256) void select_kernel(const float* __restrict__ x,
                                                     const double* __restrict__ rn64,
                                                     const int* __restrict__ cand_idx,
                                                     const float* __restrict__ cand_val,
                                                     int* __restrict__ sel,
                                                     int SEGJT, int NSEGMAX, int SHIFT) {
    const int tid  = threadIdx.x;
    const int wid  = tid >> 6;
    const int lane = tid & 63;
    const int row  = (blockIdx.x << 2) + wid;
    const int b    = row >> 12;
    const int i    = row & (T_ - 1);
    const int njt  = (i >> SHIFT) + 1;
    const int nseg = (njt + SEGJT - 1) / SEGJT;
    const int ncand = nseg * M_;              // <= 192

    __shared__ unsigned long long keys[4][192];
    __shared__ float v12[4][12];
    __shared__ int   i12[4][12];

    if (lane < 12) { v12[wid][lane] = -INFINITY; i12[wid][lane] = -1; }

    const size_t cb = (size_t)row * NSEGMAX * M_;
    float cv[3]; int cj[3]; unsigned long long kk[3];
#pragma unroll
    for (int q = 0; q < 3; ++q) {
        const int c = lane + (q << 6);
        if (c < ncand) { cv[q] = cand_val[cb + c]; cj[q] = cand_idx[cb + c]; }
        else           { cv[q] = -INFINITY;        cj[q] = -1; }
        unsigned u = __float_as_uint(cv[q]);
        unsigned so = (u & 0x80000000u) ? ~u : (u | 0x80000000u);
        kk[q] = (cj[q] >= 0)
              ? ((((unsigned long long)so) << 32) | (unsigned long long)(0xFFFFFFFFu - (unsigned)cj[q]))
              : 0ull;
        keys[wid][lane + (q << 6)] = kk[q];
    }
    int nv = 0;
#pragma unroll
    for (int q = 0; q < 3; ++q) nv += __popcll(__ballot(cj[q] >= 0));
    __syncthreads();

    int rk0 = 0, rk1 = 0, rk2 = 0;
#pragma unroll 4
    for (int c = 0; c < ncand; ++c) {
        const unsigned long long kc = keys[wid][c];
        rk0 += (kc > kk[0]);
        rk1 += (kc > kk[1]);
        rk2 += (kc > kk[2]);
    }
    if (cj[0] >= 0 && rk0 < 12) { v12[wid][rk0] = cv[0]; i12[wid][rk0] = cj[0]; }
    if (cj[1] >= 0 && rk1 < 12) { v12[wid][rk1] = cv[1]; i12[wid][rk1] = cj[1]; }
    if (cj[2] >= 0 && rk2 < 12) { v12[wid][rk2] = cv[2]; i12[wid][rk2] = cj[2]; }
    __syncthreads();

    const float v8 = v12[wid][7];
    const float v9 = v12[wid][8];
    const bool refine = (nv > K_) && (v8 - v9 < 2e-4f);   // wave-uniform

    int outj = -1;
    int cnt;
    if (refine) {
        const float* xi = x + (size_t)row * D_;
        float4 xa[4];
#pragma unroll
        for (int q = 0; q < 4; ++q)
            xa[q] = *reinterpret_cast<const float4*>(xi + (lane << 4) + (q << 2));
        double sim[12]; int jj[12];
#pragma unroll
        for (int c = 0; c < 12; ++c) {
            const int j = i12[wid][c];
            jj[c] = j;
            double s = 0.0;
            if (j >= 0) {
                const float* xj = x + ((size_t)(b << 12) + j) * D_;
#pragma unroll
                for (int q = 0; q < 4; ++q) {
                    const float4 xc = *reinterpret_cast<const float4*>(xj + (lane << 4) + (q << 2));
                    s += (double)xa[q].x * xc.x + (double)xa[q].y * xc.y +
                         (double)xa[q].z * xc.z + (double)xa[q].w * xc.w;
                }
            }
            sim[c] = s;
        }
#pragma unroll
        for (int c = 0; c < 12; ++c) {
#pragma unroll
            for (int o = 1; o < 64; o <<= 1) sim[c] += __shfl_xor(sim[c], o);
        }
        const double rni = rn64[row];
#pragma unroll
        for (int c = 0; c < 12; ++c)
            sim[c] = (jj[c] >= 0) ? sim[c] * rni * rn64[(b << 12) + jj[c]] : -1e300;
        unsigned msel = 0;
#pragma unroll
        for (int c = 0; c < 12; ++c) {
            int r = 0;
#pragma unroll
            for (int d = 0; d < 12; ++d) {
                if (d == c) continue;
                r += (sim[d] > sim[c]) || (sim[d] == sim[c] && jj[d] < jj[c]);
            }
            if (jj[c] >= 0 && r < 8) msel |= (1u << c);
        }
        cnt = __popc(msel); if (cnt < 1) cnt = 1;
        if (lane < 8) {
            int seen = 0;
#pragma unroll
            for (int c = 0; c < 12; ++c) {
                if (msel & (1u << c)) { if (seen == lane) outj = jj[c]; ++seen; }
            }
        }
    } else {
        cnt = nv < K_ ? nv : K_; if (cnt < 1) cnt = 1;
        if (lane < 8) outj = i12[wid][lane];
    }
    if (lane < 8) sel[(row << 4) + lane] = outj;
    if (lane == 8) sel[(row << 4) + 8] = cnt;
}

// ---------------- Kernel 3b: streaming gather + gate epilogue ----------------
__global__ __launch_bounds__(256) void gather_kernel(const float* __restrict__ x,
                                                     const int* __restrict__ sel,
                                                     const float* __restrict__ gain,
                                                     const float* __restrict__ bias,
                                                     const float* __restrict__ lmix,
                                                     const float* __restrict__ lscale,
                                                     float* __restrict__ out) {
    const int row = blockIdx.x;
    const int b   = row >> 12;
    const int tid = threadIdx.x;
    const int sb  = row << 4;

    int js[8];
#pragma unroll
    for (int k = 0; k < 8; ++k) js[k] = sel[sb + k];
    const int cnt = sel[sb + 8];

    const float4 xiv = reinterpret_cast<const float4*>(x + (size_t)row * D_)[tid];
    float mx = 0.f, my = 0.f, mz = 0.f, mw = 0.f;
#pragma unroll
    for (int k = 0; k < 8; ++k) {
        const int j = js[k];
        if (j >= 0) {
            const float4 xc = reinterpret_cast<const float4*>(
                x + ((size_t)(b << 12) + j) * D_)[tid];
            mx += xc.x; my += xc.y; mz += xc.z; mw += xc.w;
        }
    }
    const float inv = 1.0f / (float)cnt;
    const float lm = lmix[0], ls = lscale[0];
    const float mix = 1.0f / (1.0f + expf(-lm));
    const float sc  = (fmaxf(ls, 0.f) + log1pf(expf(-fabsf(ls)))) + 0.01f;
    const float4 g  = reinterpret_cast<const float4*>(gain)[tid];
    const float4 bb = reinterpret_cast<const float4*>(bias)[tid];

    float4 o4;
    {
        float m, bl, y;
        m = mx * inv; bl = mix * xiv.x + (1.f - mix) * m; y = bl * g.x + bb.x;
        o4.x = 0.5f * y * (1.f + erff(y * 0.70710678118654752f)) * sc;
        m = my * inv; bl = mix * xiv.y + (1.f - mix) * m; y = bl * g.y + bb.y;
        o4.y = 0.5f * y * (1.f + erff(y * 0.70710678118654752f)) * sc;
        m = mz * inv; bl = mix * xiv.z + (1.f - mix) * m; y = bl * g.z + bb.z;
        o4.z = 0.5f * y * (1.f + erff(y * 0.70710678118654752f)) * sc;
        m = mw * inv; bl = mix * xiv.w + (1.f - mix) * m; y = bl * g.w + bb.w;
        o4.w = 0.5f * y * (1.f + erff(y * 0.70710678118654752f)) * sc;
    }
    reinterpret_cast<float4*>(out + (size_t)row * D_)[tid] = o4;
}

// ---------------- launch ----------------
extern "C" void kernel_launch(void* const* d_in, const int* in_sizes, int n_in,
                              void* d_out, int out_size, void* d_ws, size_t ws_size,
                              hipStream_t stream) {
    const float* x      = (const float*)d_in[0];
    const float* gain   = (const float*)d_in[1];
    const float* bias   = (const float*)d_in[2];
    const float* lmix   = (const float*)d_in[3];
    const float* lscale = (const float*)d_in[4];
    float* out = (float*)d_out;

    char* ws = (char*)d_ws;
    float*  rn32 = (float*)ws;                        // 64 KB
    double* rn64 = (double*)(ws + 65536);             // 128 KB
    int*    selb = (int*)(ws + 196608);               // B*T*16 ints = 1 MB
    const size_t base2 = 196608 + (size_t)B_ * T_ * 16 * 4;
    const size_t HF = (size_t)B_ * T_ * D_ * 2;       // 32 MB fp16 array
    _Float16* xh = (_Float16*)(ws + base2);
    const size_t base_cand = base2 + HF;

    auto candBytes = [](int nseg) { return (size_t)B_ * T_ * nseg * M_ * 8; };

    const bool use_f16 = (ws_size >= base_cand + candBytes(NSEG_F16));

    if (use_f16) {
        int*   cidx = (int*)(ws + base_cand);
        float* cval = (float*)(ws + base_cand + candBytes(NSEG_F16) / 2);
        norm_prep_kernel<<<dim3(B_ * T_), dim3(256), 0, stream>>>(x, rn32, rn64, xh, 1);
        simtopk_f16<<<dim3(B_ * 64 * NSEG_F16), dim3(256), 0, stream>>>(xh, cidx, cval);
        select_kernel<<<dim3(B_ * T_ / 4), dim3(256), 0, stream>>>(
            x, rn64, cidx, cval, selb, SEGJT_F16, NSEG_F16, 8);
    } else {
        int SEG2, NSEG2;
        if (ws_size >= base2 + candBytes(9)) { SEG2 = 4;  NSEG2 = 9; }
        else                                 { SEG2 = 33; NSEG2 = 1; }
        int*   cidx = (int*)(ws + base2);
        float* cval = (float*)(ws + base2 + candBytes(NSEG2) / 2);
        norm_prep_kernel<<<dim3(B_ * T_), dim3(256), 0, stream>>>(x, rn32, rn64, nullptr, 0);
        simtopk_fp32<<<dim3(B_ * 128 * NSEG2), dim3(256), 0, stream>>>(x, rn32, cidx, cval, SEG2, NSEG2);
        select_kernel<<<dim3(B_ * T_ / 4), dim3(256), 0, stream>>>(
            x, rn64, cidx, cval, selb, SEG2, NSEG2, 7);
    }
    gather_kernel<<<dim3(B_ * T_), dim3(256), 0, stream>>>(
        x, selb, gain, bias, lmix, lscale, out);
}

// Round 6
// 427.239 us; speedup vs baseline: 6.4538x; 1.6108x over previous
//
#include <hip/hip_runtime.h>
#include <math.h>

#define B_ 4
#define T_ 4096
#define D_ 1024
#define K_ 8
#define M_ 12          // candidates kept per row/segment (refined to top-K)

// f16 MFMA path params
#define NSEG_F16 8     // segments of SEGJT_F16 j-tiles (256 wide) per 64-row i-tile
#define SEGJT_F16 2

// fallback fp32-path tile params
#define BI 32
#define BJ 128
#define DC 32

typedef __attribute__((ext_vector_type(8))) _Float16 f16x8;
typedef __attribute__((ext_vector_type(4))) _Float16 f16x4;
typedef __attribute__((ext_vector_type(16))) float f32x16;

// branch-free sorted insert into ascending top-12 (tv[0]=min). Static indices.
__device__ __forceinline__ void ins12(float (&tv)[M_], int (&tix)[M_], float v, int nj) {
#pragma unroll
    for (int k = 0; k < M_; ++k) {
        const float nxt = (k < M_ - 1) ? tv[k + 1] : INFINITY;
        const int   nxi = (k < M_ - 1) ? tix[k + 1] : -1;
        const bool  up  = v > nxt;
        const bool  mid = v > tv[k];
        tv[k]  = up ? nxt : (mid ? v  : tv[k]);
        tix[k] = up ? nxi : (mid ? nj : tix[k]);
    }
}

// ---------------- Kernel 1: row norms (fp64 truth) + fp16 normalized prep ----------------
__global__ __launch_bounds__(256) void norm_prep_kernel(const float* __restrict__ x,
                                                        float* __restrict__ rn32,
                                                        double* __restrict__ rn64,
                                                        _Float16* __restrict__ xh,
                                                        int do_prep) {
    const int row = blockIdx.x;
    const int tid = threadIdx.x;
    const float4 v = reinterpret_cast<const float4*>(x + (size_t)row * D_)[tid];
    double ss = (double)v.x * v.x + (double)v.y * v.y +
                (double)v.z * v.z + (double)v.w * v.w;
    for (int o = 32; o > 0; o >>= 1) ss += __shfl_down(ss, o);
    __shared__ double ws[4];
    __shared__ double s_rn;
    if ((tid & 63) == 0) ws[tid >> 6] = ss;
    __syncthreads();
    if (tid == 0) {
        double s = ws[0] + ws[1] + ws[2] + ws[3];
        double rn = 1.0 / (sqrt(s) + 1e-8);
        rn64[row] = rn;
        rn32[row] = (float)rn;
        s_rn = rn;
    }
    __syncthreads();
    if (do_prep) {
        const float rnf = (float)s_rn;
        f16x4 h;
        h[0] = (_Float16)(v.x * rnf);
        h[1] = (_Float16)(v.y * rnf);
        h[2] = (_Float16)(v.z * rnf);
        h[3] = (_Float16)(v.w * rnf);
        *reinterpret_cast<f16x4*>(xh + (size_t)row * D_ + (tid << 2)) = h;
    }
}

// ---------------- Kernel 2a: fp16 MFMA similarity, LDS-staged, one column per lane ----------------
// Block: 256 thr = 4 waves, i-tile 64 rows, j step 256 (wave w: j in [64w, 64w+64)).
// S^T tiles: A-operand = x^_j (LDS), B-operand = x^_i (LDS). C col = lane&31 -> i,
// rows = j. After K-loop, shfl_xor(32) consolidates each lane to ONE i column.
__global__ __launch_bounds__(256) void simtopk_f16(const _Float16* __restrict__ xh,
                                                   int* __restrict__ cand_idx,
                                                   float* __restrict__ cand_val) {
    __shared__ __align__(16) char smem[40960];   // JB 32KB | IB 8KB ; merge aliases 24KB

    const int bid = blockIdx.x;
    const int s   = bid & (NSEG_F16 - 1);
    const int bt  = bid >> 3;                    // NSEG_F16 = 8
    const int t   = bt & 63;
    const int b   = bt >> 6;
    const int njt = (t >> 2) + 1;                // 256-wide j-tiles covering rows [64t, 64t+63]
    const int jt0 = s * SEGJT_F16;
    if (jt0 >= njt) return;
    const int jt1 = min(jt0 + SEGJT_F16, njt);
    const int i0  = t << 6;

    const int tid  = threadIdx.x;
    const int wid  = tid >> 6;
    const int lane = tid & 63;
    const int l31  = lane & 31;
    const int lhi  = lane >> 5;
    const int sw7  = (l31 & 7);                  // row-XOR swizzle key (same for row, row+32)

    const _Float16* xb = xh + (size_t)b * T_ * D_;

    const int myc = i0 + (lhi << 5) + l31;       // the single i column this lane owns

    float tv[M_]; int tix[M_];
#pragma unroll
    for (int k = 0; k < M_; ++k) { tv[k] = -INFINITY; tix[k] = -1; }

    for (int jt = jt0; jt < jt1; ++jt) {
        const int j0  = jt << 8;
        const int jbw = j0 + (wid << 6);
        f32x16 acc00, acc01, acc10, acc11;
#pragma unroll
        for (int r = 0; r < 16; ++r) { acc00[r] = 0.f; acc01[r] = 0.f; acc10[r] = 0.f; acc11[r] = 0.f; }

        for (int kh = 0; kh < 16; ++kh) {        // K chunks of 64 elements (128 B/row)
            __syncthreads();                     // protect prior chunk reads
            // stage j-panel: 256 rows x 128B, 16B granules XOR-swizzled by row&7
#pragma unroll
            for (int it = 0; it < 8; ++it) {
                const int g   = (it << 8) + tid;
                const int row = g >> 3, c = g & 7;
                const uint4 v = *reinterpret_cast<const uint4*>(
                    xb + (size_t)(j0 + row) * D_ + (kh << 6) + (c << 3));
                *reinterpret_cast<uint4*>(smem + row * 128 + ((c ^ (row & 7)) << 4)) = v;
            }
            // stage i-panel: 64 rows x 128B at IB=32768
#pragma unroll
            for (int it = 0; it < 2; ++it) {
                const int g   = (it << 8) + tid;
                const int row = g >> 3, c = g & 7;
                const uint4 v = *reinterpret_cast<const uint4*>(
                    xb + (size_t)(i0 + row) * D_ + (kh << 6) + (c << 3));
                *reinterpret_cast<uint4*>(smem + 32768 + row * 128 + ((c ^ (row & 7)) << 4)) = v;
            }
            __syncthreads();
#pragma unroll
            for (int ks = 0; ks < 4; ++ks) {
                const int cc  = (ks << 1) + lhi;
                const int gsw = ((cc ^ sw7) << 4);
                const int ja  = ((wid << 6) + l31) * 128 + gsw;
                const f16x8 aj0 = *reinterpret_cast<const f16x8*>(smem + ja);
                const f16x8 aj1 = *reinterpret_cast<const f16x8*>(smem + ja + 4096);
                const f16x8 bi0 = *reinterpret_cast<const f16x8*>(smem + 32768 + l31 * 128 + gsw);
                const f16x8 bi1 = *reinterpret_cast<const f16x8*>(smem + 32768 + 4096 + l31 * 128 + gsw);
                acc00 = __builtin_amdgcn_mfma_f32_32x32x16_f16(aj0, bi0, acc00, 0, 0, 0);
                acc01 = __builtin_amdgcn_mfma_f32_32x32x16_f16(aj0, bi1, acc01, 0, 0, 0);
                acc10 = __builtin_amdgcn_mfma_f32_32x32x16_f16(aj1, bi0, acc10, 0, 0, 0);
                acc11 = __builtin_amdgcn_mfma_f32_32x32x16_f16(aj1, bi1, acc11, 0, 0, 0);
            }
        }
        // consolidate to one column per lane and scan 64 j-values in registers
#pragma unroll
        for (int r = 0; r < 16; ++r) {
            const float swA = __shfl_xor(acc00[r], 32);
            const float swB = __shfl_xor(acc01[r], 32);
            const float swC = __shfl_xor(acc10[r], 32);
            const float swD = __shfl_xor(acc11[r], 32);
            const int rbase = (r & 3) + ((r >> 2) << 3);
            const int rown  = jbw + rbase + (lhi << 2);        // own half rows
            const int rotn  = jbw + rbase + ((1 - lhi) << 2);  // partner half rows
            const float va = lhi ? acc01[r] : acc00[r];        // (rown,      myc)
            const float vb = lhi ? swB      : swA;             // (rotn,      myc)
            const float vc = lhi ? acc11[r] : acc10[r];        // (rown + 32, myc)
            const float vd = lhi ? swD      : swC;             // (rotn + 32, myc)
            if (rown <= myc      && va > tv[0]) ins12(tv, tix, va, rown);
            if (rotn <= myc      && vb > tv[0]) ins12(tv, tix, vb, rotn);
            if (rown + 32 <= myc && vc > tv[0]) ins12(tv, tix, vc, rown + 32);
            if (rotn + 32 <= myc && vd > tv[0]) ins12(tv, tix, vd, rotn + 32);
        }
    }

    // merge 4 wave-lists per column via LDS (staging dead)
    __syncthreads();
    float* mv = reinterpret_cast<float*>(smem);            // [64][4][12] = 12KB
    int*   mi = reinterpret_cast<int*>(smem + 12288);      // 12KB
    const int coll = (lhi << 5) + l31;
#pragma unroll
    for (int k = 0; k < M_; ++k) {
        mv[(coll * 4 + wid) * M_ + k] = tv[k];
        mi[(coll * 4 + wid) * M_ + k] = tix[k];
    }
    __syncthreads();
    if (tid < 64) {
        float gv[M_]; int gx[M_];
#pragma unroll
        for (int k = 0; k < M_; ++k) { gv[k] = -INFINITY; gx[k] = -1; }
        for (int ls = 0; ls < 4; ++ls) {
            const int base = (tid * 4 + ls) * M_;
            for (int k = M_ - 1; k >= 0; --k) {      // stored ascending; walk descending
                const float v = mv[base + k];
                if (!(v > gv[0])) break;
                const int nj = mi[base + k];
                if (nj >= 0) ins12(gv, gx, v, nj);
            }
        }
        const size_t cb = ((size_t)(b * T_ + i0 + tid) * NSEG_F16 + s) * M_;
#pragma unroll
        for (int k = 0; k < M_; ++k) {
            cand_val[cb + k] = gv[M_ - 1 - k];
            cand_idx[cb + k] = gx[M_ - 1 - k];
        }
    }
}

// ---------------- Kernel 2b: fp32 fallback (used only if workspace too small) ----------------
__global__ __launch_bounds__(256) void simtopk_fp32(const float* __restrict__ x,
                                                    const float* __restrict__ rn32,
                                                    int* __restrict__ cand_idx,
                                                    float* __restrict__ cand_val,
                                                    int SEGJT, int NSEGMAX) {
    __shared__ __align__(16) float smem[DC * 36 + DC * 132];
    float (*At)[36]  = reinterpret_cast<float(*)[36]>(smem);
    float (*Bt)[132] = reinterpret_cast<float(*)[132]>(smem + DC * 36);
    float (*Cs)[132] = reinterpret_cast<float(*)[132]>(smem);

    const int bid = blockIdx.x;
    const int s   = bid % NSEGMAX;
    const int bt  = bid / NSEGMAX;
    const int t   = bt & 127;
    const int b   = bt >> 7;
    const int njt = (t >> 2) + 1;
    const int jt0 = s * SEGJT;
    if (jt0 >= njt) return;
    const int jt1 = min(jt0 + SEGJT, njt);
    const int i0  = t * BI;

    const int tid = threadIdx.x;
    const int tx  = tid & 31;
    const int ty  = tid >> 5;
    const float* xb = x + (size_t)b * T_ * D_;
    const float* rb = rn32 + b * T_;

    const int ai  = tid >> 3;
    const int adq = (tid & 7) << 2;

    float tv[M_]; int tix[M_];
#pragma unroll
    for (int k = 0; k < M_; ++k) { tv[k] = -INFINITY; tix[k] = -1; }

    for (int jt = jt0; jt < jt1; ++jt) {
        const int j0 = jt << 7;
        float acc[4][4];
#pragma unroll
        for (int ii = 0; ii < 4; ++ii)
#pragma unroll
            for (int jj = 0; jj < 4; ++jj) acc[ii][jj] = 0.f;

        for (int dc = 0; dc < D_; dc += DC) {
            __syncthreads();
            {
                const float rn = rb[i0 + ai];
                float4 v = *reinterpret_cast<const float4*>(&xb[(size_t)(i0 + ai) * D_ + dc + adq]);
                At[adq + 0][ai] = v.x * rn;
                At[adq + 1][ai] = v.y * rn;
                At[adq + 2][ai] = v.z * rn;
                At[adq + 3][ai] = v.w * rn;
            }
#pragma unroll
            for (int l = 0; l < 4; ++l) {
                const int li = tid + (l << 8);
                const int j  = li >> 3;
                const int dq = (li & 7) << 2;
                const float rn = rb[j0 + j];
                float4 v = *reinterpret_cast<const float4*>(&xb[(size_t)(j0 + j) * D_ + dc + dq]);
                Bt[dq + 0][j] = v.x * rn;
                Bt[dq + 1][j] = v.y * rn;
                Bt[dq + 2][j] = v.z * rn;
                Bt[dq + 3][j] = v.w * rn;
            }
            __syncthreads();
#pragma unroll 8
            for (int d = 0; d < DC; ++d) {
                float4 a  = *reinterpret_cast<const float4*>(&At[d][ty << 2]);
                float4 bv = *reinterpret_cast<const float4*>(&Bt[d][tx << 2]);
                float av[4] = {a.x, a.y, a.z, a.w};
                float bw[4] = {bv.x, bv.y, bv.z, bv.w};
#pragma unroll
                for (int ii = 0; ii < 4; ++ii)
#pragma unroll
                    for (int jj = 0; jj < 4; ++jj)
                        acc[ii][jj] = fmaf(av[ii], bw[jj], acc[ii][jj]);
            }
        }
        __syncthreads();
#pragma unroll
        for (int ii = 0; ii < 4; ++ii) {
            *reinterpret_cast<float4*>(&Cs[(ty << 2) + ii][tx << 2]) =
                make_float4(acc[ii][0], acc[ii][1], acc[ii][2], acc[ii][3]);
        }
        __syncthreads();
        if (tid < BI) {
            const int gi   = i0 + tid;
            const int jmax = gi - j0;
            const int cend = jmax < BJ - 1 ? jmax : BJ - 1;
            for (int c = 0; c <= cend; ++c) {
                const float v = Cs[tid][c];
                if (v > tv[0]) ins12(tv, tix, v, j0 + c);
            }
        }
    }
    if (tid < BI) {
        const size_t base = ((size_t)(b * T_ + i0 + tid) * NSEGMAX + s) * M_;
#pragma unroll
        for (int k = 0; k < M_; ++k) {
            cand_idx[base + k] = tix[M_ - 1 - k];
            cand_val[base + k] = tv[M_ - 1 - k];
        }
    }
}

// ---------------- Kernel 3a: wave-per-row rank-merge + fp64 refine -> sel[] ----------------
__global__ __launch_bounds__(256) void select_kernel(const float* __restrict__ x,
                                                     const double* __restrict__ rn64,
                                                     const int* __restrict__ cand_idx,
                                                     const float* __restrict__ cand_val,
                                                     int* __restrict__ sel,
                                                     int SEGJT, int NSEGMAX, int SHIFT) {
    const int tid  = threadIdx.x;
    const int wid  = tid >> 6;
    const int lane = tid & 63;
    const int row  = (blockIdx.x << 2) + wid;
    const int b    = row >> 12;
    const int i    = row & (T_ - 1);
    const int njt  = (i >> SHIFT) + 1;
    const int nseg = (njt + SEGJT - 1) / SEGJT;
    const int ncand = nseg * M_;              // <= 192

    __shared__ unsigned long long keys[4][192];
    __shared__ float v12[4][12];
    __shared__ int   i12[4][12];

    if (lane < 12) { v12[wid][lane] = -INFINITY; i12[wid][lane] = -1; }

    const size_t cb = (size_t)row * NSEGMAX * M_;
    float cv[3]; int cj[3]; unsigned long long kk[3];
#pragma unroll
    for (int q = 0; q < 3; ++q) {
        const int c = lane + (q << 6);
        if (c < ncand) { cv[q] = cand_val[cb + c]; cj[q] = cand_idx[cb + c]; }
        else           { cv[q] = -INFINITY;        cj[q] = -1; }
        unsigned u = __float_as_uint(cv[q]);
        unsigned so = (u & 0x80000000u) ? ~u : (u | 0x80000000u);
        kk[q] = (cj[q] >= 0)
              ? ((((unsigned long long)so) << 32) | (unsigned long long)(0xFFFFFFFFu - (unsigned)cj[q]))
              : 0ull;
        keys[wid][lane + (q << 6)] = kk[q];
    }
    int nv = 0;
#pragma unroll
    for (int q = 0; q < 3; ++q) nv += __popcll(__ballot(cj[q] >= 0));
    __syncthreads();

    int rk0 = 0, rk1 = 0, rk2 = 0;
#pragma unroll 4
    for (int c = 0; c < ncand; ++c) {
        const unsigned long long kc = keys[wid][c];
        rk0 += (kc > kk[0]);
        rk1 += (kc > kk[1]);
        rk2 += (kc > kk[2]);
    }
    if (cj[0] >= 0 && rk0 < 12) { v12[wid][rk0] = cv[0]; i12[wid][rk0] = cj[0]; }
    if (cj[1] >= 0 && rk1 < 12) { v12[wid][rk1] = cv[1]; i12[wid][rk1] = cj[1]; }
    if (cj[2] >= 0 && rk2 < 12) { v12[wid][rk2] = cv[2]; i12[wid][rk2] = cj[2]; }
    __syncthreads();

    const float v8 = v12[wid][7];
    const float v9 = v12[wid][8];
    const bool refine = (nv > K_) && (v8 - v9 < 2e-4f);   // wave-uniform

    int outj = -1;
    int cnt;
    if (refine) {
        const float* xi = x + (size_t)row * D_;
        float4 xa[4];
#pragma unroll
        for (int q = 0; q < 4; ++q)
            xa[q] = *reinterpret_cast<const float4*>(xi + (lane << 4) + (q << 2));
        double sim[12]; int jj[12];
#pragma unroll
        for (int c = 0; c < 12; ++c) {
            const int j = i12[wid][c];
            jj[c] = j;
            double s = 0.0;
            if (j >= 0) {
                const float* xj = x + ((size_t)(b << 12) + j) * D_;
#pragma unroll
                for (int q = 0; q < 4; ++q) {
                    const float4 xc = *reinterpret_cast<const float4*>(xj + (lane << 4) + (q << 2));
                    s += (double)xa[q].x * xc.x + (double)xa[q].y * xc.y +
                         (double)xa[q].z * xc.z + (double)xa[q].w * xc.w;
                }
            }
            sim[c] = s;
        }
#pragma unroll
        for (int c = 0; c < 12; ++c) {
#pragma unroll
            for (int o = 1; o < 64; o <<= 1) sim[c] += __shfl_xor(sim[c], o);
        }
        const double rni = rn64[row];
#pragma unroll
        for (int c = 0; c < 12; ++c)
            sim[c] = (jj[c] >= 0) ? sim[c] * rni * rn64[(b << 12) + jj[c]] : -1e300;
        unsigned msel = 0;
#pragma unroll
        for (int c = 0; c < 12; ++c) {
            int r = 0;
#pragma unroll
            for (int d = 0; d < 12; ++d) {
                if (d == c) continue;
                r += (sim[d] > sim[c]) || (sim[d] == sim[c] && jj[d] < jj[c]);
            }
            if (jj[c] >= 0 && r < 8) msel |= (1u << c);
        }
        cnt = __popc(msel); if (cnt < 1) cnt = 1;
        if (lane < 8) {
            int seen = 0;
#pragma unroll
            for (int c = 0; c < 12; ++c) {
                if (msel & (1u << c)) { if (seen == lane) outj = jj[c]; ++seen; }
            }
        }
    } else {
        cnt = nv < K_ ? nv : K_; if (cnt < 1) cnt = 1;
        if (lane < 8) outj = i12[wid][lane];
    }
    if (lane < 8) sel[(row << 4) + lane] = outj;
    if (lane == 8) sel[(row << 4) + 8] = cnt;
}

// ---------------- Kernel 3b: streaming gather + gate epilogue ----------------
__global__ __launch_bounds__(256) void gather_kernel(const float* __restrict__ x,
                                                     const int* __restrict__ sel,
                                                     const float* __restrict__ gain,
                                                     const float* __restrict__ bias,
                                                     const float* __restrict__ lmix,
                                                     const float* __restrict__ lscale,
                                                     float* __restrict__ out) {
    const int row = blockIdx.x;
    const int b   = row >> 12;
    const int tid = threadIdx.x;
    const int sb  = row << 4;

    int js[8];
#pragma unroll
    for (int k = 0; k < 8; ++k) js[k] = sel[sb + k];
    const int cnt = sel[sb + 8];

    const float4 xiv = reinterpret_cast<const float4*>(x + (size_t)row * D_)[tid];
    float mx = 0.f, my = 0.f, mz = 0.f, mw = 0.f;
#pragma unroll
    for (int k = 0; k < 8; ++k) {
        const int j = js[k];
        if (j >= 0) {
            const float4 xc = reinterpret_cast<const float4*>(
                x + ((size_t)(b << 12) + j) * D_)[tid];
            mx += xc.x; my += xc.y; mz += xc.z; mw += xc.w;
        }
    }
    const float inv = 1.0f / (float)cnt;
    const float lm = lmix[0], ls = lscale[0];
    const float mix = 1.0f / (1.0f + expf(-lm));
    const float sc  = (fmaxf(ls, 0.f) + log1pf(expf(-fabsf(ls)))) + 0.01f;
    const float4 g  = reinterpret_cast<const float4*>(gain)[tid];
    const float4 bb = reinterpret_cast<const float4*>(bias)[tid];

    float4 o4;
    {
        float m, bl, y;
        m = mx * inv; bl = mix * xiv.x + (1.f - mix) * m; y = bl * g.x + bb.x;
        o4.x = 0.5f * y * (1.f + erff(y * 0.70710678118654752f)) * sc;
        m = my * inv; bl = mix * xiv.y + (1.f - mix) * m; y = bl * g.y + bb.y;
        o4.y = 0.5f * y * (1.f + erff(y * 0.70710678118654752f)) * sc;
        m = mz * inv; bl = mix * xiv.z + (1.f - mix) * m; y = bl * g.z + bb.z;
        o4.z = 0.5f * y * (1.f + erff(y * 0.70710678118654752f)) * sc;
        m = mw * inv; bl = mix * xiv.w + (1.f - mix) * m; y = bl * g.w + bb.w;
        o4.w = 0.5f * y * (1.f + erff(y * 0.70710678118654752f)) * sc;
    }
    reinterpret_cast<float4*>(out + (size_t)row * D_)[tid] = o4;
}

// ---------------- launch ----------------
extern "C" void kernel_launch(void* const* d_in, const int* in_sizes, int n_in,
                              void* d_out, int out_size, void* d_ws, size_t ws_size,
                              hipStream_t stream) {
    const float* x      = (const float*)d_in[0];
    const float* gain   = (const float*)d_in[1];
    const float* bias   = (const float*)d_in[2];
    const float* lmix   = (const float*)d_in[3];
    const float* lscale = (const float*)d_in[4];
    float* out = (float*)d_out;

    char* ws = (char*)d_ws;
    float*  rn32 = (float*)ws;                        // 64 KB
    double* rn64 = (double*)(ws + 65536);             // 128 KB
    int*    selb = (int*)(ws + 196608);               // B*T*16 ints = 1 MB
    const size_t base2 = 196608 + (size_t)B_ * T_ * 16 * 4;
    const size_t HF = (size_t)B_ * T_ * D_ * 2;       // 32 MB fp16 array
    _Float16* xh = (_Float16*)(ws + base2);
    const size_t base_cand = base2 + HF;

    auto candBytes = [](int nseg) { return (size_t)B_ * T_ * nseg * M_ * 8; };

    const bool use_f16 = (ws_size >= base_cand + candBytes(NSEG_F16));

    if (use_f16) {
        int*   cidx = (int*)(ws + base_cand);
        float* cval = (float*)(ws + base_cand + candBytes(NSEG_F16) / 2);
        norm_prep_kernel<<<dim3(B_ * T_), dim3(256), 0, stream>>>(x, rn32, rn64, xh, 1);
        simtopk_f16<<<dim3(B_ * 64 * NSEG_F16), dim3(256), 0, stream>>>(xh, cidx, cval);
        select_kernel<<<dim3(B_ * T_ / 4), dim3(256), 0, stream>>>(
            x, rn64, cidx, cval, selb, SEGJT_F16, NSEG_F16, 8);
    } else {
        int SEG2, NSEG2;
        if (ws_size >= base2 + candBytes(9)) { SEG2 = 4;  NSEG2 = 9; }
        else                                 { SEG2 = 33; NSEG2 = 1; }
        int*   cidx = (int*)(ws + base2);
        float* cval = (float*)(ws + base2 + candBytes(NSEG2) / 2);
        norm_prep_kernel<<<dim3(B_ * T_), dim3(256), 0, stream>>>(x, rn32, rn64, nullptr, 0);
        simtopk_fp32<<<dim3(B_ * 128 * NSEG2), dim3(256), 0, stream>>>(x, rn32, cidx, cval, SEG2, NSEG2);
        select_kernel<<<dim3(B_ * T_ / 4), dim3(256), 0, stream>>>(
            x, rn64, cidx, cval, selb, SEG2, NSEG2, 7);
    }
    gather_kernel<<<dim3(B_ * T_), dim3(256), 0, stream>>>(
        x, selb, gain, bias, lmix, lscale, out);
}